// Round 15
// baseline (529.825 us; speedup 1.0000x reference)
//
#include <hip/hip_runtime.h>
#include <cmath>

#define S_ 1024
#define B_ 8
#define H_ 512
#define S2_ 1022
#define M_ (B_*S2_)     // 8176
#define PAD_ 8192
#define VTS_ ((size_t)8*8*64*1024)   // VT per-branch stride (4194304 shorts)

typedef __attribute__((ext_vector_type(8))) short bf16x8;
typedef __attribute__((ext_vector_type(4))) float f32x4;
typedef __attribute__((ext_vector_type(4))) unsigned int u32x4;
typedef __attribute__((ext_vector_type(2))) unsigned int u32x2;

__device__ __forceinline__ unsigned short f2bf(float f){
  unsigned int u = __float_as_uint(f);
  return (unsigned short)((u + 0x7fffu + ((u>>16)&1u)) >> 16);
}
__device__ __forceinline__ float bf2f(unsigned short u){
  return __uint_as_float((unsigned int)u << 16);
}
// tanh-approx gelu: x*sigmoid(2*(c1 x + c2 x^3)); |err vs erf-gelu| < ~3e-4
__device__ __forceinline__ float fgelu(float x){
  float u = x * (0.7978845608f + 0.0356774081f * x * x);
  return x / (1.f + __expf(-2.f * u));
}
// raw 2^x (v_exp_f32 is natively base-2)
__device__ __forceinline__ float fexp2(float x){
  float r; asm("v_exp_f32 %0, %1" : "=v"(r) : "v"(x)); return r;
}
// hardware packed f32->bf16 (RNE), lo -> bits[15:0], hi -> bits[31:16]
__device__ __forceinline__ unsigned int cvtpk(float lo, float hi){
  unsigned int r; asm("v_cvt_pk_bf16_f32 %0, %1, %2" : "=v"(r) : "v"(lo), "v"(hi)); return r;
}

__device__ __forceinline__ void glds16(const void* g, void* l){
  __builtin_amdgcn_global_load_lds((const __attribute__((address_space(1))) unsigned int*)g,
                                   (__attribute__((address_space(3))) unsigned int*)l, 16, 0, 0);
}
#define SB() __builtin_amdgcn_sched_barrier(0)

// ---------------------------------------------------------------- prep: X = [f[:-2], bk[2:]] bf16 (M_ x 1024)
__global__ __launch_bounds__(256) void lma_prep_x(const float* __restrict__ hidden,
                                                  unsigned short* __restrict__ Xb){
  int m = blockIdx.x; int dq = threadIdx.x * 4;
  int b = m / S2_, s = m - b * S2_;
  int srow = (dq < 512) ? s : (s + 2);
  const float* src = hidden + ((size_t)srow * B_ + b) * 1024 + dq;
  f32x4 v = *(const f32x4*)src;
  union { u32x2 u; unsigned short s4[4]; } pk;
  #pragma unroll
  for (int j = 0; j < 4; j++) pk.s4[j] = f2bf(v[j]);
  *(u32x2*)&Xb[(size_t)m * 1024 + dq] = pk.u;
}

// ---------------------------------------------------------------- batched weight transpose+cast
struct TPack {
  const float* src[14];
  unsigned short* dst[14];
  int K[14];
  int N[14];
};
__global__ __launch_bounds__(256) void lma_transpose_all(TPack p){
  int idx = blockIdx.z;
  int K = p.K[idx], N = p.N[idx];
  int kb = blockIdx.x * 32, nb = blockIdx.y * 32;
  if (kb >= K || nb >= N) return;
  const float* W = p.src[idx];
  unsigned short* WT = p.dst[idx];
  __shared__ float t[32][33];
  int tx = threadIdx.x & 31, ty = threadIdx.x >> 5;
  #pragma unroll
  for (int i = ty; i < 32; i += 8) t[i][tx] = W[(size_t)(kb + i) * N + nb + tx];
  __syncthreads();
  #pragma unroll
  for (int i = ty; i < 32; i += 8) WT[(size_t)(nb + i) * K + kb + tx] = f2bf(t[tx][i]);
}

// ---------------------------------------------------------------- concat K/V biases
__global__ __launch_bounds__(256) void lma_biascat(const float* __restrict__ fk, const float* __restrict__ fv,
                                                   const float* __restrict__ bk, const float* __restrict__ bv,
                                                   float* __restrict__ out){
  int i = blockIdx.x * 256 + threadIdx.x;     // 0..2047
  int fb = i >> 10, col = i & 1023;
  const float* s = (col < 512) ? (fb ? bk : fk) : (fb ? bv : fv);
  out[i] = s[col & 511];
}

// ---------------------------------------------------------------- V (in KV2, cols 512..1023) -> VT2[fb][b][h][d][s pad 1024]
// Pad cols s in [S2_,1024) ZEROED (aliased buffer may hold bf16-NaN bit patterns).
__global__ __launch_bounds__(256) void lma_vt2(const unsigned short* __restrict__ KV2,
                                               unsigned short* __restrict__ VT2){
  __shared__ unsigned short t[32][34];
  int s0 = blockIdx.x * 32, c0 = blockIdx.y * 32;
  int z = blockIdx.z, fb = z >> 3, b = z & 7;
  const unsigned short* V = KV2 + (size_t)fb * PAD_ * 1024 + 512;
  unsigned short* VT = VT2 + (size_t)fb * VTS_;
  int tx = threadIdx.x & 31, ty = threadIdx.x >> 5;
  #pragma unroll
  for (int i = ty; i < 32; i += 8){
    int s = s0 + i; if (s > S2_-1) s = S2_-1;
    t[i][tx] = V[((size_t)b * S2_ + s) * 1024 + c0 + tx];
  }
  __syncthreads();
  int s = s0 + tx;
  #pragma unroll
  for (int i = ty; i < 32; i += 8){
    int c = c0 + i, h = c >> 6, d = c & 63;
    VT[(((size_t)b * 8 + h) * 64 + d) * 1024 + s] = (s < S2_) ? t[tx][i] : (unsigned short)0;
  }
}

// ---------------------------------------------------------------- 128^2 2-phase GEMM (kept as fallback; no call sites)
__global__ __launch_bounds__(256) void lma_gemm2(
    const unsigned short* __restrict__ A, int lda,
    const unsigned short* __restrict__ Bt0, const unsigned short* __restrict__ Bt1,
    const float* __restrict__ bias0, const float* __restrict__ bias1,
    void* __restrict__ Cout, int ldc,
    int M, int N, int K, int mode, int amap, int nmt)
{
  __shared__ unsigned short Al[128*32];
  __shared__ unsigned short Bl[128*32];
  const int tid = threadIdx.x;
  const int w = tid >> 6, lane = tid & 63, quad = lane >> 4, l16 = lane & 15;
  const int mt = blockIdx.x % nmt, nt = blockIdx.x / nmt;
  const int m0 = mt * 128, n0 = nt * 128;
  const int brch = m0 >> 13;
  const unsigned short* Bt = brch ? Bt1 : Bt0;
  const float* bias = brch ? bias1 : bias0;
  const int coloff = (amap == 2 && brch) ? 512 : 0;
  const int wm = (w >> 1) * 64, wn = (w & 1) * 64;

  f32x4 acc[4][4];
  #pragma unroll
  for (int i = 0; i < 4; i++)
    #pragma unroll
    for (int f = 0; f < 4; f++) acc[i][f] = f32x4{0.f,0.f,0.f,0.f};

  const int srow = lane >> 2;
  const int spc  = (((lane & 3) ^ ((lane >> 3) & 3))) * 8;
  const int rswz = (l16 >> 1) & 3;

  for (int k0 = 0; k0 < K; k0 += 32) {
    #pragma unroll
    for (int c = 0; c < 2; c++) {
      int ra = w*32 + c*16 + srow;
      int ga = m0 + ra;
      int ar;
      if (amap == 0) { ar = (ga > M-1) ? (M-1) : ga; }
      else { ar = ga & (PAD_-1); if (ar > M_-1) ar = M_-1; }
      glds16(A + (size_t)ar * lda + coloff + k0 + spc, &Al[(w*32 + c*16) * 32]);
      int gb = n0 + ra; if (gb > N-1) gb = N-1;
      glds16(Bt + (size_t)gb * K + k0 + spc, &Bl[(w*32 + c*16) * 32]);
    }
    __syncthreads();
    bf16x8 af[4], bfr[4];
    #pragma unroll
    for (int i = 0; i < 4; i++) af[i]  = *(const bf16x8*)&Al[(wm + i*16 + l16)*32 + ((quad ^ rswz) * 8)];
    #pragma unroll
    for (int f = 0; f < 4; f++) bfr[f] = *(const bf16x8*)&Bl[(wn + f*16 + l16)*32 + ((quad ^ rswz) * 8)];
    #pragma unroll
    for (int i = 0; i < 4; i++)
      #pragma unroll
      for (int f = 0; f < 4; f++)
        acc[i][f] = __builtin_amdgcn_mfma_f32_16x16x32_bf16(af[i], bfr[f], acc[i][f], 0, 0, 0);
    __syncthreads();
  }

  float bv[4];
  #pragma unroll
  for (int f = 0; f < 4; f++) bv[f] = bias ? bias[n0 + wn + f*16 + l16] : 0.f;
  const int col0 = n0 + wn + l16;
  #pragma unroll
  for (int i = 0; i < 4; i++) {
    #pragma unroll
    for (int r = 0; r < 4; r++) {
      int row = m0 + wm + i*16 + quad*4 + r;
      if (row < M) {
        #pragma unroll
        for (int f = 0; f < 4; f++) {
          float v = acc[i][f][r] + bv[f];
          if (mode == 2) v = fgelu(v);
          else if (mode == 1) v *= 0.18033688011112042f;
          if (mode <= 2) ((unsigned short*)Cout)[(size_t)row * ldc + col0 + f*16] = f2bf(v);
          else if (mode == 3) ((float*)Cout)[(size_t)row * ldc + col0 + f*16] = v;
          else {
            int sr = row % S2_, bb2 = row / S2_;
            ((float*)Cout)[((size_t)sr * B_ + bb2) * ldc + col0 + f*16] = v;
          }
        }
      }
    }
  }
}

// ---------------------------------------------------------------- 256^2 8-phase GEMM v4 (T2+T3+T4+T5; fence diet, r12-measured win)
__global__ __launch_bounds__(512, 2) void lma_gemm8(
    const unsigned short* __restrict__ A, int lda,
    const unsigned short* __restrict__ Bt0, const unsigned short* __restrict__ Bt1,
    const float* __restrict__ bias0, const float* __restrict__ bias1,
    unsigned short* __restrict__ Cout, int ldc,
    int M, int N, int K, int mode, int amap, int nmt)
{
  __shared__ unsigned short Ls[2][2][256*64];   // [buf][0=A,1=B][row*64+k]
  const int tid = threadIdx.x;
  const int w = tid >> 6, lane = tid & 63, quad = lane >> 4, l16 = lane & 15;
  const int mt = blockIdx.x % nmt, nt = blockIdx.x / nmt;
  const int m0 = mt * 256, n0 = nt * 256;
  const int brch = m0 >> 13;
  const unsigned short* Bt = brch ? Bt1 : Bt0;
  const float* bias = brch ? bias1 : bias0;
  const int coloff = (amap == 2 && brch) ? 512 : 0;
  const int wm = (w >> 2) * 128, wn = (w & 3) * 64;

  f32x4 acc[8][4];
  #pragma unroll
  for (int i = 0; i < 8; i++)
    #pragma unroll
    for (int f = 0; f < 4; f++) acc[i][f] = f32x4{0.f,0.f,0.f,0.f};

  const int lrow8 = lane >> 3;
  const int lkb   = lane & 7;
  const int NT = K >> 6;

  const unsigned short* aP[2][2]; const unsigned short* bP[2][2];
  int aD[2][2], bD[2][2];
  #pragma unroll
  for (int hf = 0; hf < 2; hf++)
    #pragma unroll
    for (int c = 0; c < 2; c++) {
      int rtA = (w>>2)*128 + hf*64 + ((w&3)*2 + c)*8 + lrow8;
      int kbA = lkb ^ (rtA & 7);
      int ga = m0 + rtA;
      int ar;
      if (amap == 0) { ar = (ga > M-1) ? (M-1) : ga; }
      else { ar = ga & (PAD_-1); if (ar > M_-1) ar = M_-1; }
      aP[hf][c] = A + (size_t)ar * lda + coloff + kbA*8;
      aD[hf][c] = ((w>>2)*128 + hf*64 + ((w&3)*2 + c)*8) * 64;
      int rtB = (w>>1)*64 + hf*32 + ((w&1)*2 + c)*8 + lrow8;
      int kbB = lkb ^ (rtB & 7);
      int gb = n0 + rtB; if (gb > N-1) gb = N-1;
      bP[hf][c] = Bt + (size_t)gb * K + kbB*8;
      bD[hf][c] = ((w>>1)*64 + hf*32 + ((w&1)*2 + c)*8) * 64;
    }

  bf16x8 af[4][2], bf[2][2];

  #define STA(buf, hf, kt) { _Pragma("unroll") for (int c = 0; c < 2; c++) \
      glds16(aP[hf][c] + (size_t)(kt)*64, &Ls[buf][0][aD[hf][c]]); }
  #define STB(buf, hf, kt) { _Pragma("unroll") for (int c = 0; c < 2; c++) \
      glds16(bP[hf][c] + (size_t)(kt)*64, &Ls[buf][1][bD[hf][c]]); }
  #define LDA8(buf, mq) { _Pragma("unroll") for (int j = 0; j < 4; j++){ \
      int rt = wm + (mq)*64 + j*16 + l16; \
      const unsigned short* base = &Ls[buf][0][rt*64]; \
      int f_ = rt & 7; \
      af[j][0] = *(const bf16x8*)(base + ((    quad) ^ f_)*8); \
      af[j][1] = *(const bf16x8*)(base + ((4 + quad) ^ f_)*8); } }
  #define LDB8(buf, nq) { _Pragma("unroll") for (int j = 0; j < 2; j++){ \
      int rt = wn + (nq)*32 + j*16 + l16; \
      const unsigned short* base = &Ls[buf][1][rt*64]; \
      int f_ = rt & 7; \
      bf[j][0] = *(const bf16x8*)(base + ((    quad) ^ f_)*8); \
      bf[j][1] = *(const bf16x8*)(base + ((4 + quad) ^ f_)*8); } }
  #define MFMAQ(mq, nq) { __builtin_amdgcn_s_setprio(1); \
      _Pragma("unroll") for (int j = 0; j < 4; j++) \
        _Pragma("unroll") for (int j2 = 0; j2 < 2; j2++){ \
          acc[(mq)*4+j][(nq)*2+j2] = __builtin_amdgcn_mfma_f32_16x16x32_bf16(af[j][0], bf[j2][0], acc[(mq)*4+j][(nq)*2+j2], 0, 0, 0); \
          acc[(mq)*4+j][(nq)*2+j2] = __builtin_amdgcn_mfma_f32_16x16x32_bf16(af[j][1], bf[j2][1], acc[(mq)*4+j][(nq)*2+j2], 0, 0, 0); } \
      __builtin_amdgcn_s_setprio(0); }
  #define BAR()   { __builtin_amdgcn_s_barrier(); }
  #define LGKM0() { asm volatile("s_waitcnt lgkmcnt(0)" ::: "memory"); SB(); }
  #define VM6()   { asm volatile("s_waitcnt vmcnt(6)"   ::: "memory"); }
  #define VM2()   { asm volatile("s_waitcnt vmcnt(2)"   ::: "memory"); }

  STA(0, 0, 0); STB(0, 0, 0); STB(0, 1, 0); STA(0, 1, 0);
  STA(1, 0, 1);
  asm volatile("s_waitcnt vmcnt(2)" ::: "memory");
  BAR();

  const int NI = NT >> 1;
  for (int i = 0; i < NI; i++) {
    const int tb  = 2*i + 1;
    int ta2 = 2*i + 2; if (ta2 > NT-1) ta2 = NT-1;
    int tb2 = 2*i + 3; if (tb2 > NT-1) tb2 = NT-1;

    LDA8(0, 0); LDB8(0, 0); STB(1, 0, tb);
    BAR(); LGKM0(); MFMAQ(0, 0); BAR();
    LDB8(0, 1); STB(1, 1, tb);
    BAR(); LGKM0(); MFMAQ(0, 1); BAR();
    LDA8(0, 1); STA(1, 1, tb);
    BAR(); LGKM0(); MFMAQ(1, 1); BAR();
    LDB8(0, 0); STA(0, 0, ta2);
    BAR(); LGKM0(); MFMAQ(1, 0); VM6(); BAR();
    LDA8(1, 0); LDB8(1, 0); STB(0, 1, ta2);
    BAR(); LGKM0(); MFMAQ(0, 0); VM6(); BAR();
    LDB8(1, 1); STA(0, 1, ta2);
    BAR(); LGKM0(); MFMAQ(0, 1); VM6(); BAR();
    LDA8(1, 1); STB(0, 0, ta2);
    BAR(); LGKM0(); MFMAQ(1, 1); BAR();
    LDB8(1, 0); STA(1, 0, tb2);
    BAR(); LGKM0(); MFMAQ(1, 0); VM2(); BAR();
  }
  asm volatile("s_waitcnt vmcnt(0)" ::: "memory");

  float bv[4];
  #pragma unroll
  for (int f = 0; f < 4; f++) bv[f] = bias ? bias[n0 + wn + f*16 + l16] : 0.f;
  const int col0 = n0 + wn + l16;
  #pragma unroll
  for (int i2 = 0; i2 < 8; i2++) {
    #pragma unroll
    for (int r = 0; r < 4; r++) {
      int row = m0 + wm + i2*16 + quad*4 + r;
      if (row < M) {
        #pragma unroll
        for (int f = 0; f < 4; f++) {
          float v = acc[i2][f][r] + bv[f];
          if (mode == 2) v = fgelu(v);
          Cout[(size_t)row * ldc + col0 + f*16] = f2bf(v);
        }
      }
    }
  }
  #undef STA
  #undef STB
  #undef LDA8
  #undef LDB8
  #undef MFMAQ
  #undef BAR
  #undef LGKM0
  #undef VM6
  #undef VM2
}

// ---------------------------------------------------------------- 128x256 8-phase GEMM (gemm8w) v2 — fence diet (r12-measured win)
__global__ __launch_bounds__(512, 2) void lma_gemm8w(
    const unsigned short* __restrict__ A, int lda,
    const unsigned short* __restrict__ Bt0, const unsigned short* __restrict__ Bt1,
    const float* __restrict__ bias0, const float* __restrict__ bias1,
    void* __restrict__ Cout, int ldc,
    int M, int N, int K, int mode, int nmt)
{
  __shared__ unsigned short LsA[2][128*64];   // 2 x 16KB
  __shared__ unsigned short LsB[2][256*64];   // 2 x 32KB
  const int tid = threadIdx.x;
  const int w = tid >> 6, lane = tid & 63, quad = lane >> 4, l16 = lane & 15;
  const int mt = blockIdx.x % nmt, nt = blockIdx.x / nmt;
  const int m0 = mt * 128, n0 = nt * 256;
  const int brch = m0 >> 13;
  const unsigned short* Bt = brch ? Bt1 : Bt0;
  const float* bias = brch ? bias1 : bias0;
  const int wm = (w >> 2) * 64, wn = (w & 3) * 64;

  f32x4 acc[4][4];
  #pragma unroll
  for (int i = 0; i < 4; i++)
    #pragma unroll
    for (int f = 0; f < 4; f++) acc[i][f] = f32x4{0.f,0.f,0.f,0.f};

  const int lrow8 = lane >> 3;
  const int lkb   = lane & 7;
  const int NT = K >> 6;

  const unsigned short* aP[2]; int aD[2];
  const unsigned short* bP[2][2]; int bD[2][2];
  #pragma unroll
  for (int hf = 0; hf < 2; hf++) {
    int rtA = hf*64 + w*8 + lrow8;
    int kbA = lkb ^ (rtA & 7);
    int ga = m0 + rtA; if (ga > M-1) ga = M-1;
    aP[hf] = A + (size_t)ga * lda + kbA*8;
    aD[hf] = (hf*64 + w*8) * 64;
    #pragma unroll
    for (int c = 0; c < 2; c++) {
      int rtB = hf*128 + (w*2 + c)*8 + lrow8;
      int kbB = lkb ^ (rtB & 7);
      int gb = n0 + rtB; if (gb > N-1) gb = N-1;
      bP[hf][c] = Bt + (size_t)gb * K + kbB*8;
      bD[hf][c] = (hf*128 + (w*2 + c)*8) * 64;
    }
  }

  bf16x8 af[2][2], bf[2][2];

  #define WSTA(buf, hf, kt) { glds16(aP[hf] + (size_t)(kt)*64, &LsA[buf][aD[hf]]); }
  #define WSTB(buf, hf, kt) { _Pragma("unroll") for (int c = 0; c < 2; c++) \
      glds16(bP[hf][c] + (size_t)(kt)*64, &LsB[buf][bD[hf][c]]); }
  #define WLDA(buf, mq) { _Pragma("unroll") for (int j = 0; j < 2; j++){ \
      int rt = wm + (mq)*32 + j*16 + l16; \
      const unsigned short* base = &LsA[buf][rt*64]; \
      int f_ = rt & 7; \
      af[j][0] = *(const bf16x8*)(base + ((    quad) ^ f_)*8); \
      af[j][1] = *(const bf16x8*)(base + ((4 + quad) ^ f_)*8); } }
  #define WLDB(buf, nq) { _Pragma("unroll") for (int j = 0; j < 2; j++){ \
      int rt = wn + (nq)*32 + j*16 + l16; \
      const unsigned short* base = &LsB[buf][rt*64]; \
      int f_ = rt & 7; \
      bf[j][0] = *(const bf16x8*)(base + ((    quad) ^ f_)*8); \
      bf[j][1] = *(const bf16x8*)(base + ((4 + quad) ^ f_)*8); } }
  #define WMFMAQ(mq, nq) { __builtin_amdgcn_s_setprio(1); \
      _Pragma("unroll") for (int j = 0; j < 2; j++) \
        _Pragma("unroll") for (int j2 = 0; j2 < 2; j2++){ \
          acc[(mq)*2+j][(nq)*2+j2] = __builtin_amdgcn_mfma_f32_16x16x32_bf16(af[j][0], bf[j2][0], acc[(mq)*2+j][(nq)*2+j2], 0, 0, 0); \
          acc[(mq)*2+j][(nq)*2+j2] = __builtin_amdgcn_mfma_f32_16x16x32_bf16(af[j][1], bf[j2][1], acc[(mq)*2+j][(nq)*2+j2], 0, 0, 0); } \
      __builtin_amdgcn_s_setprio(0); }
  #define WBAR()   { __builtin_amdgcn_s_barrier(); }
  #define WLGKM0() { asm volatile("s_waitcnt lgkmcnt(0)" ::: "memory"); SB(); }
  #define WVM4()   { asm volatile("s_waitcnt vmcnt(4)"   ::: "memory"); }
  #define WVM1()   { asm volatile("s_waitcnt vmcnt(1)"   ::: "memory"); }

  WSTA(0, 0, 0); WSTB(0, 0, 0); WSTB(0, 1, 0); WSTA(0, 1, 0);
  WSTA(1, 0, 1);
  WVM1(); WBAR();

  const int NI = NT >> 1;
  for (int i = 0; i < NI; i++) {
    const int tb  = 2*i + 1;
    int ta2 = 2*i + 2; if (ta2 > NT-1) ta2 = NT-1;
    int tb2 = 2*i + 3; if (tb2 > NT-1) tb2 = NT-1;

    WLDA(0, 0); WLDB(0, 0); WSTB(1, 0, tb);
    WBAR(); WLGKM0(); WMFMAQ(0, 0); WBAR();
    WLDB(0, 1); WSTB(1, 1, tb);
    WBAR(); WLGKM0(); WMFMAQ(0, 1); WBAR();
    WLDA(0, 1); WSTA(1, 1, tb);
    WBAR(); WLGKM0(); WMFMAQ(1, 1); WBAR();
    WLDB(0, 0); WSTA(0, 0, ta2);
    WBAR(); WLGKM0(); WMFMAQ(1, 0); WVM4(); WBAR();
    WLDA(1, 0); WLDB(1, 0); WSTB(0, 1, ta2);
    WBAR(); WLGKM0(); WMFMAQ(0, 0); WVM4(); WBAR();
    WLDB(1, 1); WSTA(0, 1, ta2);
    WBAR(); WLGKM0(); WMFMAQ(0, 1); WVM4(); WBAR();
    WLDA(1, 1); WSTB(0, 0, ta2);
    WBAR(); WLGKM0(); WMFMAQ(1, 1); WBAR();
    WLDB(1, 0); WSTA(1, 0, tb2);
    WBAR(); WLGKM0(); WMFMAQ(1, 0); WVM1(); WBAR();
  }
  asm volatile("s_waitcnt vmcnt(0)" ::: "memory");

  float bv[4];
  #pragma unroll
  for (int f = 0; f < 4; f++) bv[f] = bias ? bias[n0 + wn + f*16 + l16] : 0.f;
  const int col0 = n0 + wn + l16;
  #pragma unroll
  for (int i2 = 0; i2 < 4; i2++) {
    #pragma unroll
    for (int r = 0; r < 4; r++) {
      int row = m0 + wm + i2*16 + quad*4 + r;
      if (row < M) {
        #pragma unroll
        for (int f = 0; f < 4; f++) {
          float v = acc[i2][f][r] + bv[f];
          if (mode == 2) v = fgelu(v);
          else if (mode == 1) v *= 0.18033688011112042f;   // 0.125 * log2(e)
          if (mode <= 2) ((unsigned short*)Cout)[(size_t)row * ldc + col0 + f*16] = f2bf(v);
          else if (mode == 3) ((float*)Cout)[(size_t)row * ldc + col0 + f*16] = v;
          else {
            int sr = row % S2_, bb2 = row / S2_;
            ((float*)Cout)[((size_t)sr * B_ + bb2) * ldc + col0 + f*16] = v;
          }
        }
      }
    }
  }
  #undef WSTA
  #undef WSTB
  #undef WLDA
  #undef WLDB
  #undef WMFMAQ
  #undef WBAR
  #undef WLGKM0
  #undef WVM4
  #undef WVM1
}

// ---------------------------------------------------------------- block reduction helper
__device__ __forceinline__ void lma_red2(float& s, float& sq){
  __shared__ float red[16];
  #pragma unroll
  for (int msk = 1; msk < 64; msk <<= 1){ s += __shfl_xor(s, msk); sq += __shfl_xor(sq, msk); }
  int w = threadIdx.x >> 6;
  if ((threadIdx.x & 63) == 0){ red[w] = s; red[8 + w] = sq; }
  __syncthreads();
  s  = red[0] + red[1] + red[2] + red[3];
  sq = red[8] + red[9] + red[10] + red[11];
}

// ---------------------------------------------------------------- generic LN (f32 in, bf16 or f32 out)
__global__ __launch_bounds__(256) void lma_ln(const float* __restrict__ in,
                                              const float* __restrict__ g, const float* __restrict__ bb,
                                              int D, unsigned short* __restrict__ obf, float* __restrict__ of32){
  int row = blockIdx.x, t = threadIdx.x;
  const float* x = in + (size_t)row * D;
  float s = 0.f, sq = 0.f;
  for (int d = t; d < D; d += 256){ float v = x[d]; s += v; sq += v * v; }
  lma_red2(s, sq);
  float mean = s / D;
  float var = sq / D - mean * mean;
  float rstd = rsqrtf(fmaxf(var, 0.f) + 1e-12f);
  if (obf) {
    for (int d = t; d < D; d += 256) obf[(size_t)row * D + d] = f2bf((x[d] - mean) * rstd * g[d] + bb[d]);
  } else {
    for (int d = t; d < D; d += 256) of32[(size_t)row * D + d] = (x[d] - mean) * rstd * g[d] + bb[d];
  }
}

// ---------------------------------------------------------------- branch-combined LN over T12b (bf16, D=512) -> LQ2 bf16
__global__ __launch_bounds__(256) void lma_ln2(const unsigned short* __restrict__ T12b,
                                               const float* __restrict__ fg, const float* __restrict__ fbb,
                                               const float* __restrict__ bg, const float* __restrict__ bbb,
                                               unsigned short* __restrict__ LQ2){
  int m = blockIdx.x, t = threadIdx.x;           // 0..2*M_-1
  int fb = (m >= M_);
  int idx = m - fb * M_;
  const float* g = fb ? bg : fg;
  const float* bb = fb ? bbb : fbb;
  const unsigned short* x = T12b + ((size_t)fb * PAD_ + idx) * 512;
  unsigned short* o = LQ2 + ((size_t)fb * PAD_ + idx) * 512;
  float v0 = bf2f(x[t]), v1 = bf2f(x[t + 256]);
  float s = v0 + v1, sq = v0*v0 + v1*v1;
  lma_red2(s, sq);
  float mean = s / 512.f;
  float var = sq / 512.f - mean * mean;
  float rstd = rsqrtf(fmaxf(var, 0.f) + 1e-12f);
  o[t]       = f2bf((v0 - mean) * rstd * g[t]       + bb[t]);
  o[t + 256] = f2bf((v1 - mean) * rstd * g[t + 256] + bb[t + 256]);
}

// ---------------------------------------------------------------- attn LN: LN(residual(hidden)+[pf,pb](bf16)) -> bf16 (M_ x 1024)
__global__ __launch_bounds__(256) void lma_attn_ln(const unsigned short* __restrict__ pf,
                                                   const unsigned short* __restrict__ pb,
                                                   const float* __restrict__ hidden,
                                                   const float* __restrict__ g, const float* __restrict__ bb,
                                                   unsigned short* __restrict__ out){
  int m = blockIdx.x, t = threadIdx.x;
  int b = m / S2_, s = m - b * S2_;
  const float* hf = hidden + ((size_t)s       * B_ + b) * 1024;
  const float* hb = hidden + ((size_t)(s + 2) * B_ + b) * 1024;
  float v[4]; float sum = 0.f, sq = 0.f;
  #pragma unroll
  for (int j = 0; j < 4; j++){
    int d = t + j * 256;
    float x = (d < 512) ? (bf2f(pf[(size_t)m * 512 + d]) + hf[d])
                        : (bf2f(pb[(size_t)m * 512 + (d - 512)]) + hb[d]);
    v[j] = x; sum += x; sq += x * x;
  }
  lma_red2(sum, sq);
  float mean = sum / 1024.f;
  float var = sq / 1024.f - mean * mean;
  float rstd = rsqrtf(fmaxf(var, 0.f) + 1e-12f);
  #pragma unroll
  for (int j = 0; j < 4; j++){
    int d = t + j * 256;
    out[(size_t)m * 1024 + d] = f2bf((v[j] - mean) * rstd * g[d] + bb[d]);
  }
}

// ---------------------------------------------------------------- combined flash attention v12b: 32 q-rows/wave, VGPR cap 256
// r13's v12 structure was RIGHT (attn is LDS-read-throughput-bound: 4 waves/SIMD
// x 32 ds_read_b128 x ~12cyc = 6.1k cyc/slot = measured 6.35k; MfmaUtil pred
// 9.8% = measured 10.7%) but launch_bounds(256,4)'s 128-VGPR cap made the
// compiler pick a 64-VGPR budget and spill the doubled state (~8MB scratch,
// WRITE 16.3->24.5MB, 126us). v12b: IDENTICAL code with launch_bounds(256,2)
// -> 256-VGPR cap; the ~140-VGPR peak allocates cleanly. Each wave owns TWO
// 16-row q-subtiles -> each K/V element consumed by half the wave-iterations
// -> total LDS-read volume HALVES. Correctness harness-proven in r13.
__global__ __launch_bounds__(256, 2) void lma_attn12(const unsigned short* __restrict__ Q2,
                                                     const unsigned short* __restrict__ KV2,
                                                     const unsigned short* __restrict__ VT2,
                                                     unsigned short* __restrict__ CT2,
                                                     const int* __restrict__ lens){
  __shared__ unsigned short Kl[64*64];
  __shared__ unsigned short Vl[64*64];
  __shared__ __align__(16) unsigned short Pl[4][2*16*64];   // 4KB/wave (2 subtiles)

  const int tid = threadIdx.x;
  const int w = tid >> 6, lane = tid & 63, quad = lane >> 4, l16 = lane & 15;
  const int id = blockIdx.x;                 // [fb:1][qt:3][h:3][b:3]
  const int b = id & 7, h = (id >> 3) & 7, qt = (id >> 6) & 7, fb = id >> 9;
  const int backward = fb;
  const int L2 = lens[b] - 2;
  const int q0wg = qt * 128;

  int q0s[2], qgs[2], qls[2];
  #pragma unroll
  for (int s = 0; s < 2; s++){
    q0s[s] = q0wg + (w + 4*s) * 16;
    qgs[s] = q0s[s] + l16;
    qls[s] = (qgs[s] > S2_-1) ? (S2_-1) : qgs[s];
  }

  const size_t qbase  = ((size_t)b * S2_) * 512  + h * 64;
  const size_t kbase  = ((size_t)b * S2_) * 1024 + h * 64;
  const size_t vtbase = ((size_t)(b * 8 + h) * 64) * 1024;
  char* Pb = (char*)&Pl[w][0];

  const int lrow = lane >> 3;
  const int g0s  = (lane & 7) ^ lrow;
  const int x7   = l16 & 7;
  const int x7s  = x7 << 4;

  const unsigned short* Q  = Q2  + (size_t)fb * PAD_ * 512;
  const unsigned short* Kx = KV2 + (size_t)fb * PAD_ * 1024;
  const unsigned short* VT = VT2 + (size_t)fb * VTS_;
  unsigned short* CTX      = CT2 + (size_t)fb * PAD_ * 512;

  bf16x8 qf[2][2];
  #pragma unroll
  for (int s = 0; s < 2; s++){
    const unsigned short* qp = Q + qbase + (size_t)qls[s] * 512 + quad * 8;
    qf[s][0] = *(const bf16x8*)(qp);
    qf[s][1] = *(const bf16x8*)(qp + 32);
  }

  float mi[2] = {-3e38f, -3e38f}, li[2] = {0.f, 0.f};
  f32x4 ot[2][4];
  #pragma unroll
  for (int s = 0; s < 2; s++)
    #pragma unroll
    for (int f = 0; f < 4; f++) ot[s][f] = f32x4{0.f,0.f,0.f,0.f};

  int klo = 0, khi = S2_ - 1;
  if (q0wg + 127 < L2) {
    if (!backward) khi = q0wg + 127;
    else { klo = q0wg; khi = L2 - 1; }
  }

  for (int kt0 = klo; kt0 <= khi; kt0 += 64) {
    #pragma unroll
    for (int c = 0; c < 2; c++) {
      int r = w*16 + c*8 + lrow;
      int kr = kt0 + r; if (kr > S2_-1) kr = S2_-1;
      glds16(Kx + kbase + (size_t)kr * 1024 + g0s * 8, &Kl[(w*16 + c*8) * 64]);
      glds16(VT + vtbase + (size_t)r * 1024 + kt0 + g0s * 8, &Vl[(w*16 + c*8) * 64]);
    }
    __syncthreads();

    // kf read ONCE, used for both q-subtiles
    f32x4 st[2][4];
    {
      bf16x8 kf[4][2];
      #pragma unroll
      for (int sub = 0; sub < 4; sub++) {
        const unsigned short* kp = &Kl[(sub*16 + l16) * 64];
        kf[sub][0] = *(const bf16x8*)(kp + (( quad      ^ x7) * 8));
        kf[sub][1] = *(const bf16x8*)(kp + (((quad + 4) ^ x7) * 8));
      }
      __builtin_amdgcn_s_setprio(1);
      #pragma unroll
      for (int s = 0; s < 2; s++)
        #pragma unroll
        for (int sub = 0; sub < 4; sub++) {
          f32x4 acc = f32x4{0.f,0.f,0.f,0.f};
          acc = __builtin_amdgcn_mfma_f32_16x16x32_bf16(kf[sub][0], qf[s][0], acc, 0, 0, 0);
          acc = __builtin_amdgcn_mfma_f32_16x16x32_bf16(kf[sub][1], qf[s][1], acc, 0, 0, 0);
          st[s][sub] = acc;
        }
      __builtin_amdgcn_s_setprio(0);
    }

    // per-subtile mask (with wave-uniform interior skip)
    {
      bool tail = (kt0 + 63 > S2_ - 1);
      #pragma unroll
      for (int s = 0; s < 2; s++) {
        bool full;
        if (!backward) full = !tail && ((kt0 + 63 <= q0s[s]) || (q0s[s] >= L2));
        else           full = !tail && ((q0s[s] >= L2) || ((kt0 >= q0s[s] + 15) && (kt0 + 63 < L2)));
        if (!full) {
          #pragma unroll
          for (int sub = 0; sub < 4; sub++) {
            #pragma unroll
            for (int r = 0; r < 4; r++) {
              int kg = kt0 + sub*16 + quad*4 + r;
              bool ok;
              if (!backward) ok = (kg < S2_) && ((qgs[s] >= L2) || (kg <= qgs[s]));
              else           ok = (kg < S2_) && ((qgs[s] >= L2) || ((kg >= qgs[s]) && (kg < L2)));
              if (!ok) st[s][sub][r] = -3e38f;
            }
          }
        }
      }
    }

    // softmax per subtile (defer-max T13)
    #pragma unroll
    for (int s = 0; s < 2; s++) {
      float mx = -3e38f;
      #pragma unroll
      for (int sub = 0; sub < 4; sub++)
        #pragma unroll
        for (int r = 0; r < 4; r++) mx = fmaxf(mx, st[s][sub][r]);
      mx = fmaxf(mx, __shfl_xor(mx, 16));
      mx = fmaxf(mx, __shfl_xor(mx, 32));
      if (__any(mx > mi[s] + 11.f)) {
        float mn = fmaxf(mi[s], mx);
        float al = fexp2(mi[s] - mn);
        li[s] *= al;
        #pragma unroll
        for (int f = 0; f < 4; f++)
          #pragma unroll
          for (int r = 0; r < 4; r++) ot[s][f][r] *= al;
        mi[s] = mn;
      }
      float rs = 0.f;
      #pragma unroll
      for (int sub = 0; sub < 4; sub++)
        #pragma unroll
        for (int r = 0; r < 4; r++) {
          float p = fexp2(st[s][sub][r] - mi[s]);
          st[s][sub][r] = p; rs += p;
        }
      rs += __shfl_xor(rs, 16);
      rs += __shfl_xor(rs, 32);
      li[s] += rs;
    }

    // store BOTH P subtiles (st dies), then read vf once and run both PVs
    #pragma unroll
    for (int s = 0; s < 2; s++) {
      char* Pbs = Pb + s * 2048;
      #pragma unroll
      for (int sub = 0; sub < 4; sub++) {
        u32x2 pk2;
        pk2[0] = cvtpk(st[s][sub][0], st[s][sub][1]);
        pk2[1] = cvtpk(st[s][sub][2], st[s][sub][3]);
        *(u32x2*)(Pbs + (l16*128 + ((sub*32 + quad*8) ^ x7s))) = pk2;
      }
    }
    {
      bf16x8 vf[4][2];
      #pragma unroll
      for (int f = 0; f < 4; f++) {
        const unsigned short* vp = &Vl[(f*16 + l16) * 64];
        vf[f][0] = *(const bf16x8*)(vp + (( quad      ^ x7) * 8));
        vf[f][1] = *(const bf16x8*)(vp + (((quad + 4) ^ x7) * 8));
      }
      #pragma unroll
      for (int s = 0; s < 2; s++) {
        char* Pbs = Pb + s * 2048;
        bf16x8 pfr0 = *(const bf16x8*)(Pbs + (l16*128 + (( 0 + quad*16) ^ x7s)));
        bf16x8 pfr1 = *(const bf16x8*)(Pbs + (l16*128 + ((64 + quad*16) ^ x7s)));
        __builtin_amdgcn_s_setprio(1);
        #pragma unroll
        for (int f = 0; f < 4; f++) {
          ot[s][f] = __builtin_amdgcn_mfma_f32_16x16x32_bf16(vf[f][0], pfr0, ot[s][f], 0, 0, 0);
          ot[s][f] = __builtin_amdgcn_mfma_f32_16x16x32_bf16(vf[f][1], pfr1, ot[s][f], 0, 0, 0);
        }
        __builtin_amdgcn_s_setprio(0);
      }
    }
    __syncthreads();
  }

  #pragma unroll
  for (int s = 0; s < 2; s++) {
    if (qgs[s] < S2_) {
      float rcp = 1.f / li[s];
      #pragma unroll
      for (int f = 0; f < 4; f++) {
        ushort4 pk;
        pk.x = f2bf(ot[s][f][0] * rcp); pk.y = f2bf(ot[s][f][1] * rcp);
        pk.z = f2bf(ot[s][f][2] * rcp); pk.w = f2bf(ot[s][f][3] * rcp);
        *(ushort4*)&CTX[qbase + (size_t)qgs[s] * 512 + f*16 + quad*4] = pk;
      }
    }
  }
}

// ----------------------------------------------------------------
extern "C" void kernel_launch(void* const* d_in, const int* in_sizes, int n_in,
                              void* d_out, int out_size, void* d_ws, size_t ws_size,
                              hipStream_t stream)
{
  const float* hidden = (const float*)d_in[0];
  const int*   lens   = (const int*)d_in[1];
  const float* fw[14]; for (int i = 0; i < 14; i++) fw[i] = (const float*)d_in[2 + i];
  const float* bw[14]; for (int i = 0; i < 14; i++) bw[i] = (const float*)d_in[16 + i];
  const float* attn_g = (const float*)d_in[30];
  const float* attn_b = (const float*)d_in[31];
  const float* o_w1 = (const float*)d_in[32];
  const float* o_b1 = (const float*)d_in[33];
  const float* o_w2 = (const float*)d_in[34];
  const float* o_b2 = (const float*)d_in[35];
  const float* o_lng = (const float*)d_in[36];
  const float* o_lnb = (const float*)d_in[37];

  char* ws = (char*)d_ws;
  size_t off = 0;
  auto alloc = [&](size_t bytes)->char* {
    off = (off + 255) & ~(size_t)255;
    char* p = ws + off; off += bytes; return p;
  };

  unsigned short* fw1t = (unsigned short*)alloc((size_t)1024*1024*2);
  unsigned short* fw2t = (unsigned short*)alloc((size_t)512*1024*2);
  unsigned short* fqt  = (unsigned short*)alloc((size_t)512*512*2);
  unsigned short* fkvt = (unsigned short*)alloc((size_t)1024*512*2);  // [K(512 rows); V(512 rows)]
  unsigned short* fot  = (unsigned short*)alloc((size_t)512*512*2);
  unsigned short* bw1t = (unsigned short*)alloc((size_t)1024*1024*2);
  unsigned short* bw2t = (unsigned short*)alloc((size_t)512*1024*2);
  unsigned short* bqt  = (unsigned short*)alloc((size_t)512*512*2);
  unsigned short* bkvt = (unsigned short*)alloc((size_t)1024*512*2);
  unsigned short* bot  = (unsigned short*)alloc((size_t)512*512*2);
  unsigned short* ow1t = (unsigned short*)alloc((size_t)1024*1024*2);
  unsigned short* ow2t = (unsigned short*)alloc((size_t)1024*1024*2);
  float*          biasKV = (float*)alloc(2048*4);

  unsigned short* Xb   = (unsigned short*)alloc((size_t)M_*1024*2);
  unsigned short* big1 = (unsigned short*)alloc((size_t)2*PAD_*1024*2);
  float*          big2 = (float*)alloc((size_t)2*PAD_*512*4);
  unsigned short* LQCT = (unsigned short*)alloc((size_t)2*PAD_*512*2);
  unsigned short* Q2   = (unsigned short*)alloc((size_t)2*PAD_*512*2);

  unsigned short* H12 = big1, *KV2 = big1, *H1o = big1;
  // big2 partitions: [0 .. 2*VTS_) = T12b (bf16) then VT2 (bf16);
  //                  [2*VTS_ .. 4*VTS_) = P2b (bf16 out-proj). Exactly fills big2.
  unsigned short* T12b = (unsigned short*)big2;
  unsigned short* VT2  = (unsigned short*)big2;
  unsigned short* P2b  = (unsigned short*)big2 + 2*VTS_;
  unsigned short* LQ2 = LQCT, *CT2 = LQCT;

  lma_prep_x<<<M_, 256, 0, stream>>>(hidden, Xb);

  {
    TPack tp;
    const float* srcs[14] = { fw[0], fw[2], fw[6], fw[8], fw[10], fw[12],
                              bw[0], bw[2], bw[6], bw[8], bw[10], bw[12],
                              o_w1, o_w2 };
    unsigned short* dsts[14] = { fw1t, fw2t, fqt, fkvt, fkvt + (size_t)512*512, fot,
                                 bw1t, bw2t, bqt, bkvt, bkvt + (size_t)512*512, bot,
                                 ow1t, ow2t };
    int Ks[14] = {1024,1024,512,512,512,512, 1024,1024,512,512,512,512, 1024,1024};
    int Ns[14] = {1024, 512,512,512,512,512, 1024, 512,512,512,512,512, 1024,1024};
    for (int i = 0; i < 14; i++){ tp.src[i]=srcs[i]; tp.dst[i]=dsts[i]; tp.K[i]=Ks[i]; tp.N[i]=Ns[i]; }
    lma_transpose_all<<<dim3(32, 32, 14), 256, 0, stream>>>(tp);
  }
  lma_biascat<<<8, 256, 0, stream>>>(fw[9], fw[11], bw[9], bw[11], biasKV);

  auto G8 = [&](const unsigned short* A, int lda,
                const unsigned short* B0, const unsigned short* B1,
                const float* b0, const float* b1,
                unsigned short* C, int ldc, int M, int N, int K, int mode, int amap){
    int nmt = M / 256;
    lma_gemm8<<<dim3(nmt * (N/256)), 512, 0, stream>>>(A, lda, B0, B1, b0, b1, C, ldc, M, N, K, mode, amap, nmt);
  };
  auto G8W = [&](const unsigned short* A, int lda,
                 const unsigned short* B0, const unsigned short* B1,
                 const float* b0, const float* b1,
                 void* C, int ldc, int M, int N, int K, int mode){
    int nmt = (M + 127) / 128;
    lma_gemm8w<<<dim3(nmt * (N/256)), 512, 0, stream>>>(A, lda, B0, B1, b0, b1, C, ldc, M, N, K, mode, nmt);
  };

  // both-branch FFN + LN + projections (rows<8192 = forward, >=8192 = backward)
  G8(Xb, 1024, fw1t, bw1t, fw[1], bw[1], H12, 1024, 2*PAD_, 1024, 1024, 2, 1);   // FFN1+gelu (256^2 8-phase)
  G8W(H12, 1024, fw2t, bw2t, fw[3], bw[3], T12b, 512, 2*PAD_, 512, 1024, 0);     // FFN2 -> bf16 (128x256 8-phase)
  lma_ln2<<<2*M_, 256, 0, stream>>>(T12b, fw[4], fw[5], bw[4], bw[5], LQ2);
  G8W(LQ2, 512, fqt, bqt, fw[7], bw[7], Q2, 512, 2*PAD_, 512, 512, 1);           // Q (x0.125*log2e)
  G8(Xb, 1024, fkvt, bkvt, biasKV, biasKV + 1024, KV2, 1024, 2*PAD_, 1024, 512, 0, 2); // K|V (256^2 8-phase)
  lma_vt2<<<dim3(32, 16, 16), 256, 0, stream>>>(KV2, VT2);

  lma_attn12<<<dim3(1024), 256, 0, stream>>>(Q2, KV2, VT2, CT2, lens);

  G8W(CT2, 512, fot, bot, fw[13], bw[13], P2b, 512, 2*PAD_, 512, 512, 0);        // out proj -> bf16

  lma_attn_ln<<<M_, 256, 0, stream>>>(P2b, P2b + (size_t)PAD_*512, hidden, attn_g, attn_b, Xb);

  G8W(Xb, 1024, ow1t, ow1t, o_b1, o_b1, H1o, 1024, M_, 1024, 1024, 2);           // out FFN1+gelu
  G8W(H1o, 1024, ow2t, ow2t, o_b2, o_b2, (float*)d_out, 1024, M_, 1024, 1024, 4); // out FFN2 -> d_out (remapped)
  lma_ln<<<M_, 256, 0, stream>>>((float*)d_out, o_lng, o_lnb, 1024, nullptr, (float*)d_out);
}

// Round 16
// 517.583 us; speedup vs baseline: 1.0237x; 1.0237x over previous
//
#include <hip/hip_runtime.h>
#include <cmath>

#define S_ 1024
#define B_ 8
#define H_ 512
#define S2_ 1022
#define M_ (B_*S2_)     // 8176
#define PAD_ 8192
#define VTS_ ((size_t)8*8*64*1024)   // VT per-branch stride (4194304 shorts)

typedef __attribute__((ext_vector_type(8))) short bf16x8;
typedef __attribute__((ext_vector_type(4))) float f32x4;
typedef __attribute__((ext_vector_type(4))) unsigned int u32x4;
typedef __attribute__((ext_vector_type(2))) unsigned int u32x2;

__device__ __forceinline__ unsigned short f2bf(float f){
  unsigned int u = __float_as_uint(f);
  return (unsigned short)((u + 0x7fffu + ((u>>16)&1u)) >> 16);
}
__device__ __forceinline__ float bf2f(unsigned short u){
  return __uint_as_float((unsigned int)u << 16);
}
// tanh-approx gelu: x*sigmoid(2*(c1 x + c2 x^3)); |err vs erf-gelu| < ~3e-4
__device__ __forceinline__ float fgelu(float x){
  float u = x * (0.7978845608f + 0.0356774081f * x * x);
  return x / (1.f + __expf(-2.f * u));
}
// raw 2^x (v_exp_f32 is natively base-2)
__device__ __forceinline__ float fexp2(float x){
  float r; asm("v_exp_f32 %0, %1" : "=v"(r) : "v"(x)); return r;
}
// hardware packed f32->bf16 (RNE), lo -> bits[15:0], hi -> bits[31:16]
__device__ __forceinline__ unsigned int cvtpk(float lo, float hi){
  unsigned int r; asm("v_cvt_pk_bf16_f32 %0, %1, %2" : "=v"(r) : "v"(lo), "v"(hi)); return r;
}

__device__ __forceinline__ void glds16(const void* g, void* l){
  __builtin_amdgcn_global_load_lds((const __attribute__((address_space(1))) unsigned int*)g,
                                   (__attribute__((address_space(3))) unsigned int*)l, 16, 0, 0);
}
#define SB() __builtin_amdgcn_sched_barrier(0)

// ---------------------------------------------------------------- prep: X = [f[:-2], bk[2:]] bf16 (M_ x 1024)
__global__ __launch_bounds__(256) void lma_prep_x(const float* __restrict__ hidden,
                                                  unsigned short* __restrict__ Xb){
  int m = blockIdx.x; int dq = threadIdx.x * 4;
  int b = m / S2_, s = m - b * S2_;
  int srow = (dq < 512) ? s : (s + 2);
  const float* src = hidden + ((size_t)srow * B_ + b) * 1024 + dq;
  f32x4 v = *(const f32x4*)src;
  union { u32x2 u; unsigned short s4[4]; } pk;
  #pragma unroll
  for (int j = 0; j < 4; j++) pk.s4[j] = f2bf(v[j]);
  *(u32x2*)&Xb[(size_t)m * 1024 + dq] = pk.u;
}

// ---------------------------------------------------------------- batched weight transpose+cast
struct TPack {
  const float* src[14];
  unsigned short* dst[14];
  int K[14];
  int N[14];
};
__global__ __launch_bounds__(256) void lma_transpose_all(TPack p){
  int idx = blockIdx.z;
  int K = p.K[idx], N = p.N[idx];
  int kb = blockIdx.x * 32, nb = blockIdx.y * 32;
  if (kb >= K || nb >= N) return;
  const float* W = p.src[idx];
  unsigned short* WT = p.dst[idx];
  __shared__ float t[32][33];
  int tx = threadIdx.x & 31, ty = threadIdx.x >> 5;
  #pragma unroll
  for (int i = ty; i < 32; i += 8) t[i][tx] = W[(size_t)(kb + i) * N + nb + tx];
  __syncthreads();
  #pragma unroll
  for (int i = ty; i < 32; i += 8) WT[(size_t)(nb + i) * K + kb + tx] = f2bf(t[tx][i]);
}

// ---------------------------------------------------------------- concat K/V biases
__global__ __launch_bounds__(256) void lma_biascat(const float* __restrict__ fk, const float* __restrict__ fv,
                                                   const float* __restrict__ bk, const float* __restrict__ bv,
                                                   float* __restrict__ out){
  int i = blockIdx.x * 256 + threadIdx.x;     // 0..2047
  int fb = i >> 10, col = i & 1023;
  const float* s = (col < 512) ? (fb ? bk : fk) : (fb ? bv : fv);
  out[i] = s[col & 511];
}

// ---------------------------------------------------------------- V (in KV2, cols 512..1023) -> VT2[fb][b][h][d][s pad 1024]
// Pad cols s in [S2_,1024) ZEROED (aliased buffer may hold bf16-NaN bit patterns).
__global__ __launch_bounds__(256) void lma_vt2(const unsigned short* __restrict__ KV2,
                                               unsigned short* __restrict__ VT2){
  __shared__ unsigned short t[32][34];
  int s0 = blockIdx.x * 32, c0 = blockIdx.y * 32;
  int z = blockIdx.z, fb = z >> 3, b = z & 7;
  const unsigned short* V = KV2 + (size_t)fb * PAD_ * 1024 + 512;
  unsigned short* VT = VT2 + (size_t)fb * VTS_;
  int tx = threadIdx.x & 31, ty = threadIdx.x >> 5;
  #pragma unroll
  for (int i = ty; i < 32; i += 8){
    int s = s0 + i; if (s > S2_-1) s = S2_-1;
    t[i][tx] = V[((size_t)b * S2_ + s) * 1024 + c0 + tx];
  }
  __syncthreads();
  int s = s0 + tx;
  #pragma unroll
  for (int i = ty; i < 32; i += 8){
    int c = c0 + i, h = c >> 6, d = c & 63;
    VT[(((size_t)b * 8 + h) * 64 + d) * 1024 + s] = (s < S2_) ? t[tx][i] : (unsigned short)0;
  }
}

// ---------------------------------------------------------------- 128^2 2-phase GEMM (kept as fallback; no call sites)
__global__ __launch_bounds__(256) void lma_gemm2(
    const unsigned short* __restrict__ A, int lda,
    const unsigned short* __restrict__ Bt0, const unsigned short* __restrict__ Bt1,
    const float* __restrict__ bias0, const float* __restrict__ bias1,
    void* __restrict__ Cout, int ldc,
    int M, int N, int K, int mode, int amap, int nmt)
{
  __shared__ unsigned short Al[128*32];
  __shared__ unsigned short Bl[128*32];
  const int tid = threadIdx.x;
  const int w = tid >> 6, lane = tid & 63, quad = lane >> 4, l16 = lane & 15;
  const int mt = blockIdx.x % nmt, nt = blockIdx.x / nmt;
  const int m0 = mt * 128, n0 = nt * 128;
  const int brch = m0 >> 13;
  const unsigned short* Bt = brch ? Bt1 : Bt0;
  const float* bias = brch ? bias1 : bias0;
  const int coloff = (amap == 2 && brch) ? 512 : 0;
  const int wm = (w >> 1) * 64, wn = (w & 1) * 64;

  f32x4 acc[4][4];
  #pragma unroll
  for (int i = 0; i < 4; i++)
    #pragma unroll
    for (int f = 0; f < 4; f++) acc[i][f] = f32x4{0.f,0.f,0.f,0.f};

  const int srow = lane >> 2;
  const int spc  = (((lane & 3) ^ ((lane >> 3) & 3))) * 8;
  const int rswz = (l16 >> 1) & 3;

  for (int k0 = 0; k0 < K; k0 += 32) {
    #pragma unroll
    for (int c = 0; c < 2; c++) {
      int ra = w*32 + c*16 + srow;
      int ga = m0 + ra;
      int ar;
      if (amap == 0) { ar = (ga > M-1) ? (M-1) : ga; }
      else { ar = ga & (PAD_-1); if (ar > M_-1) ar = M_-1; }
      glds16(A + (size_t)ar * lda + coloff + k0 + spc, &Al[(w*32 + c*16) * 32]);
      int gb = n0 + ra; if (gb > N-1) gb = N-1;
      glds16(Bt + (size_t)gb * K + k0 + spc, &Bl[(w*32 + c*16) * 32]);
    }
    __syncthreads();
    bf16x8 af[4], bfr[4];
    #pragma unroll
    for (int i = 0; i < 4; i++) af[i]  = *(const bf16x8*)&Al[(wm + i*16 + l16)*32 + ((quad ^ rswz) * 8)];
    #pragma unroll
    for (int f = 0; f < 4; f++) bfr[f] = *(const bf16x8*)&Bl[(wn + f*16 + l16)*32 + ((quad ^ rswz) * 8)];
    #pragma unroll
    for (int i = 0; i < 4; i++)
      #pragma unroll
      for (int f = 0; f < 4; f++)
        acc[i][f] = __builtin_amdgcn_mfma_f32_16x16x32_bf16(af[i], bfr[f], acc[i][f], 0, 0, 0);
    __syncthreads();
  }

  float bv[4];
  #pragma unroll
  for (int f = 0; f < 4; f++) bv[f] = bias ? bias[n0 + wn + f*16 + l16] : 0.f;
  const int col0 = n0 + wn + l16;
  #pragma unroll
  for (int i = 0; i < 4; i++) {
    #pragma unroll
    for (int r = 0; r < 4; r++) {
      int row = m0 + wm + i*16 + quad*4 + r;
      if (row < M) {
        #pragma unroll
        for (int f = 0; f < 4; f++) {
          float v = acc[i][f][r] + bv[f];
          if (mode == 2) v = fgelu(v);
          else if (mode == 1) v *= 0.18033688011112042f;
          if (mode <= 2) ((unsigned short*)Cout)[(size_t)row * ldc + col0 + f*16] = f2bf(v);
          else if (mode == 3) ((float*)Cout)[(size_t)row * ldc + col0 + f*16] = v;
          else {
            int sr = row % S2_, bb2 = row / S2_;
            ((float*)Cout)[((size_t)sr * B_ + bb2) * ldc + col0 + f*16] = v;
          }
        }
      }
    }
  }
}

// ---------------------------------------------------------------- 256^2 8-phase GEMM v4 (T2+T3+T4+T5; fence diet, r12-measured win)
__global__ __launch_bounds__(512, 2) void lma_gemm8(
    const unsigned short* __restrict__ A, int lda,
    const unsigned short* __restrict__ Bt0, const unsigned short* __restrict__ Bt1,
    const float* __restrict__ bias0, const float* __restrict__ bias1,
    unsigned short* __restrict__ Cout, int ldc,
    int M, int N, int K, int mode, int amap, int nmt)
{
  __shared__ unsigned short Ls[2][2][256*64];   // [buf][0=A,1=B][row*64+k]
  const int tid = threadIdx.x;
  const int w = tid >> 6, lane = tid & 63, quad = lane >> 4, l16 = lane & 15;
  const int mt = blockIdx.x % nmt, nt = blockIdx.x / nmt;
  const int m0 = mt * 256, n0 = nt * 256;
  const int brch = m0 >> 13;
  const unsigned short* Bt = brch ? Bt1 : Bt0;
  const float* bias = brch ? bias1 : bias0;
  const int coloff = (amap == 2 && brch) ? 512 : 0;
  const int wm = (w >> 2) * 128, wn = (w & 3) * 64;

  f32x4 acc[8][4];
  #pragma unroll
  for (int i = 0; i < 8; i++)
    #pragma unroll
    for (int f = 0; f < 4; f++) acc[i][f] = f32x4{0.f,0.f,0.f,0.f};

  const int lrow8 = lane >> 3;
  const int lkb   = lane & 7;
  const int NT = K >> 6;

  const unsigned short* aP[2][2]; const unsigned short* bP[2][2];
  int aD[2][2], bD[2][2];
  #pragma unroll
  for (int hf = 0; hf < 2; hf++)
    #pragma unroll
    for (int c = 0; c < 2; c++) {
      int rtA = (w>>2)*128 + hf*64 + ((w&3)*2 + c)*8 + lrow8;
      int kbA = lkb ^ (rtA & 7);
      int ga = m0 + rtA;
      int ar;
      if (amap == 0) { ar = (ga > M-1) ? (M-1) : ga; }
      else { ar = ga & (PAD_-1); if (ar > M_-1) ar = M_-1; }
      aP[hf][c] = A + (size_t)ar * lda + coloff + kbA*8;
      aD[hf][c] = ((w>>2)*128 + hf*64 + ((w&3)*2 + c)*8) * 64;
      int rtB = (w>>1)*64 + hf*32 + ((w&1)*2 + c)*8 + lrow8;
      int kbB = lkb ^ (rtB & 7);
      int gb = n0 + rtB; if (gb > N-1) gb = N-1;
      bP[hf][c] = Bt + (size_t)gb * K + kbB*8;
      bD[hf][c] = ((w>>1)*64 + hf*32 + ((w&1)*2 + c)*8) * 64;
    }

  bf16x8 af[4][2], bf[2][2];

  #define STA(buf, hf, kt) { _Pragma("unroll") for (int c = 0; c < 2; c++) \
      glds16(aP[hf][c] + (size_t)(kt)*64, &Ls[buf][0][aD[hf][c]]); }
  #define STB(buf, hf, kt) { _Pragma("unroll") for (int c = 0; c < 2; c++) \
      glds16(bP[hf][c] + (size_t)(kt)*64, &Ls[buf][1][bD[hf][c]]); }
  #define LDA8(buf, mq) { _Pragma("unroll") for (int j = 0; j < 4; j++){ \
      int rt = wm + (mq)*64 + j*16 + l16; \
      const unsigned short* base = &Ls[buf][0][rt*64]; \
      int f_ = rt & 7; \
      af[j][0] = *(const bf16x8*)(base + ((    quad) ^ f_)*8); \
      af[j][1] = *(const bf16x8*)(base + ((4 + quad) ^ f_)*8); } }
  #define LDB8(buf, nq) { _Pragma("unroll") for (int j = 0; j < 2; j++){ \
      int rt = wn + (nq)*32 + j*16 + l16; \
      const unsigned short* base = &Ls[buf][1][rt*64]; \
      int f_ = rt & 7; \
      bf[j][0] = *(const bf16x8*)(base + ((    quad) ^ f_)*8); \
      bf[j][1] = *(const bf16x8*)(base + ((4 + quad) ^ f_)*8); } }
  #define MFMAQ(mq, nq) { __builtin_amdgcn_s_setprio(1); \
      _Pragma("unroll") for (int j = 0; j < 4; j++) \
        _Pragma("unroll") for (int j2 = 0; j2 < 2; j2++){ \
          acc[(mq)*4+j][(nq)*2+j2] = __builtin_amdgcn_mfma_f32_16x16x32_bf16(af[j][0], bf[j2][0], acc[(mq)*4+j][(nq)*2+j2], 0, 0, 0); \
          acc[(mq)*4+j][(nq)*2+j2] = __builtin_amdgcn_mfma_f32_16x16x32_bf16(af[j][1], bf[j2][1], acc[(mq)*4+j][(nq)*2+j2], 0, 0, 0); } \
      __builtin_amdgcn_s_setprio(0); }
  #define BAR()   { __builtin_amdgcn_s_barrier(); }
  #define LGKM0() { asm volatile("s_waitcnt lgkmcnt(0)" ::: "memory"); SB(); }
  #define VM6()   { asm volatile("s_waitcnt vmcnt(6)"   ::: "memory"); }
  #define VM2()   { asm volatile("s_waitcnt vmcnt(2)"   ::: "memory"); }

  STA(0, 0, 0); STB(0, 0, 0); STB(0, 1, 0); STA(0, 1, 0);
  STA(1, 0, 1);
  asm volatile("s_waitcnt vmcnt(2)" ::: "memory");
  BAR();

  const int NI = NT >> 1;
  for (int i = 0; i < NI; i++) {
    const int tb  = 2*i + 1;
    int ta2 = 2*i + 2; if (ta2 > NT-1) ta2 = NT-1;
    int tb2 = 2*i + 3; if (tb2 > NT-1) tb2 = NT-1;

    LDA8(0, 0); LDB8(0, 0); STB(1, 0, tb);
    BAR(); LGKM0(); MFMAQ(0, 0); BAR();
    LDB8(0, 1); STB(1, 1, tb);
    BAR(); LGKM0(); MFMAQ(0, 1); BAR();
    LDA8(0, 1); STA(1, 1, tb);
    BAR(); LGKM0(); MFMAQ(1, 1); BAR();
    LDB8(0, 0); STA(0, 0, ta2);
    BAR(); LGKM0(); MFMAQ(1, 0); VM6(); BAR();
    LDA8(1, 0); LDB8(1, 0); STB(0, 1, ta2);
    BAR(); LGKM0(); MFMAQ(0, 0); VM6(); BAR();
    LDB8(1, 1); STA(0, 1, ta2);
    BAR(); LGKM0(); MFMAQ(0, 1); VM6(); BAR();
    LDA8(1, 1); STB(0, 0, ta2);
    BAR(); LGKM0(); MFMAQ(1, 1); BAR();
    LDB8(1, 0); STA(1, 0, tb2);
    BAR(); LGKM0(); MFMAQ(1, 0); VM2(); BAR();
  }
  asm volatile("s_waitcnt vmcnt(0)" ::: "memory");

  float bv[4];
  #pragma unroll
  for (int f = 0; f < 4; f++) bv[f] = bias ? bias[n0 + wn + f*16 + l16] : 0.f;
  const int col0 = n0 + wn + l16;
  #pragma unroll
  for (int i2 = 0; i2 < 8; i2++) {
    #pragma unroll
    for (int r = 0; r < 4; r++) {
      int row = m0 + wm + i2*16 + quad*4 + r;
      if (row < M) {
        #pragma unroll
        for (int f = 0; f < 4; f++) {
          float v = acc[i2][f][r] + bv[f];
          if (mode == 2) v = fgelu(v);
          Cout[(size_t)row * ldc + col0 + f*16] = f2bf(v);
        }
      }
    }
  }
  #undef STA
  #undef STB
  #undef LDA8
  #undef LDB8
  #undef MFMAQ
  #undef BAR
  #undef LGKM0
  #undef VM6
  #undef VM2
}

// ---------------------------------------------------------------- 128x256 8-phase GEMM (gemm8w) v2 — fence diet (r12-measured win)
__global__ __launch_bounds__(512, 2) void lma_gemm8w(
    const unsigned short* __restrict__ A, int lda,
    const unsigned short* __restrict__ Bt0, const unsigned short* __restrict__ Bt1,
    const float* __restrict__ bias0, const float* __restrict__ bias1,
    void* __restrict__ Cout, int ldc,
    int M, int N, int K, int mode, int nmt)
{
  __shared__ unsigned short LsA[2][128*64];   // 2 x 16KB
  __shared__ unsigned short LsB[2][256*64];   // 2 x 32KB
  const int tid = threadIdx.x;
  const int w = tid >> 6, lane = tid & 63, quad = lane >> 4, l16 = lane & 15;
  const int mt = blockIdx.x % nmt, nt = blockIdx.x / nmt;
  const int m0 = mt * 128, n0 = nt * 256;
  const int brch = m0 >> 13;
  const unsigned short* Bt = brch ? Bt1 : Bt0;
  const float* bias = brch ? bias1 : bias0;
  const int wm = (w >> 2) * 64, wn = (w & 3) * 64;

  f32x4 acc[4][4];
  #pragma unroll
  for (int i = 0; i < 4; i++)
    #pragma unroll
    for (int f = 0; f < 4; f++) acc[i][f] = f32x4{0.f,0.f,0.f,0.f};

  const int lrow8 = lane >> 3;
  const int lkb   = lane & 7;
  const int NT = K >> 6;

  const unsigned short* aP[2]; int aD[2];
  const unsigned short* bP[2][2]; int bD[2][2];
  #pragma unroll
  for (int hf = 0; hf < 2; hf++) {
    int rtA = hf*64 + w*8 + lrow8;
    int kbA = lkb ^ (rtA & 7);
    int ga = m0 + rtA; if (ga > M-1) ga = M-1;
    aP[hf] = A + (size_t)ga * lda + kbA*8;
    aD[hf] = (hf*64 + w*8) * 64;
    #pragma unroll
    for (int c = 0; c < 2; c++) {
      int rtB = hf*128 + (w*2 + c)*8 + lrow8;
      int kbB = lkb ^ (rtB & 7);
      int gb = n0 + rtB; if (gb > N-1) gb = N-1;
      bP[hf][c] = Bt + (size_t)gb * K + kbB*8;
      bD[hf][c] = (hf*128 + (w*2 + c)*8) * 64;
    }
  }

  bf16x8 af[2][2], bf[2][2];

  #define WSTA(buf, hf, kt) { glds16(aP[hf] + (size_t)(kt)*64, &LsA[buf][aD[hf]]); }
  #define WSTB(buf, hf, kt) { _Pragma("unroll") for (int c = 0; c < 2; c++) \
      glds16(bP[hf][c] + (size_t)(kt)*64, &LsB[buf][bD[hf][c]]); }
  #define WLDA(buf, mq) { _Pragma("unroll") for (int j = 0; j < 2; j++){ \
      int rt = wm + (mq)*32 + j*16 + l16; \
      const unsigned short* base = &LsA[buf][rt*64]; \
      int f_ = rt & 7; \
      af[j][0] = *(const bf16x8*)(base + ((    quad) ^ f_)*8); \
      af[j][1] = *(const bf16x8*)(base + ((4 + quad) ^ f_)*8); } }
  #define WLDB(buf, nq) { _Pragma("unroll") for (int j = 0; j < 2; j++){ \
      int rt = wn + (nq)*32 + j*16 + l16; \
      const unsigned short* base = &LsB[buf][rt*64]; \
      int f_ = rt & 7; \
      bf[j][0] = *(const bf16x8*)(base + ((    quad) ^ f_)*8); \
      bf[j][1] = *(const bf16x8*)(base + ((4 + quad) ^ f_)*8); } }
  #define WMFMAQ(mq, nq) { __builtin_amdgcn_s_setprio(1); \
      _Pragma("unroll") for (int j = 0; j < 2; j++) \
        _Pragma("unroll") for (int j2 = 0; j2 < 2; j2++){ \
          acc[(mq)*2+j][(nq)*2+j2] = __builtin_amdgcn_mfma_f32_16x16x32_bf16(af[j][0], bf[j2][0], acc[(mq)*2+j][(nq)*2+j2], 0, 0, 0); \
          acc[(mq)*2+j][(nq)*2+j2] = __builtin_amdgcn_mfma_f32_16x16x32_bf16(af[j][1], bf[j2][1], acc[(mq)*2+j][(nq)*2+j2], 0, 0, 0); } \
      __builtin_amdgcn_s_setprio(0); }
  #define WBAR()   { __builtin_amdgcn_s_barrier(); }
  #define WLGKM0() { asm volatile("s_waitcnt lgkmcnt(0)" ::: "memory"); SB(); }
  #define WVM4()   { asm volatile("s_waitcnt vmcnt(4)"   ::: "memory"); }
  #define WVM1()   { asm volatile("s_waitcnt vmcnt(1)"   ::: "memory"); }

  WSTA(0, 0, 0); WSTB(0, 0, 0); WSTB(0, 1, 0); WSTA(0, 1, 0);
  WSTA(1, 0, 1);
  WVM1(); WBAR();

  const int NI = NT >> 1;
  for (int i = 0; i < NI; i++) {
    const int tb  = 2*i + 1;
    int ta2 = 2*i + 2; if (ta2 > NT-1) ta2 = NT-1;
    int tb2 = 2*i + 3; if (tb2 > NT-1) tb2 = NT-1;

    WLDA(0, 0); WLDB(0, 0); WSTB(1, 0, tb);
    WBAR(); WLGKM0(); WMFMAQ(0, 0); WBAR();
    WLDB(0, 1); WSTB(1, 1, tb);
    WBAR(); WLGKM0(); WMFMAQ(0, 1); WBAR();
    WLDA(0, 1); WSTA(1, 1, tb);
    WBAR(); WLGKM0(); WMFMAQ(1, 1); WBAR();
    WLDB(0, 0); WSTA(0, 0, ta2);
    WBAR(); WLGKM0(); WMFMAQ(1, 0); WVM4(); WBAR();
    WLDA(1, 0); WLDB(1, 0); WSTB(0, 1, ta2);
    WBAR(); WLGKM0(); WMFMAQ(0, 0); WVM4(); WBAR();
    WLDB(1, 1); WSTA(0, 1, ta2);
    WBAR(); WLGKM0(); WMFMAQ(0, 1); WVM4(); WBAR();
    WLDA(1, 1); WSTB(0, 0, ta2);
    WBAR(); WLGKM0(); WMFMAQ(1, 1); WBAR();
    WLDB(1, 0); WSTA(1, 0, tb2);
    WBAR(); WLGKM0(); WMFMAQ(1, 0); WVM1(); WBAR();
  }
  asm volatile("s_waitcnt vmcnt(0)" ::: "memory");

  float bv[4];
  #pragma unroll
  for (int f = 0; f < 4; f++) bv[f] = bias ? bias[n0 + wn + f*16 + l16] : 0.f;
  const int col0 = n0 + wn + l16;
  #pragma unroll
  for (int i2 = 0; i2 < 4; i2++) {
    #pragma unroll
    for (int r = 0; r < 4; r++) {
      int row = m0 + wm + i2*16 + quad*4 + r;
      if (row < M) {
        #pragma unroll
        for (int f = 0; f < 4; f++) {
          float v = acc[i2][f][r] + bv[f];
          if (mode == 2) v = fgelu(v);
          else if (mode == 1) v *= 0.18033688011112042f;   // 0.125 * log2(e)
          if (mode <= 2) ((unsigned short*)Cout)[(size_t)row * ldc + col0 + f*16] = f2bf(v);
          else if (mode == 3) ((float*)Cout)[(size_t)row * ldc + col0 + f*16] = v;
          else {
            int sr = row % S2_, bb2 = row / S2_;
            ((float*)Cout)[((size_t)sr * B_ + bb2) * ldc + col0 + f*16] = v;
          }
        }
      }
    }
  }
  #undef WSTA
  #undef WSTB
  #undef WLDA
  #undef WLDB
  #undef WMFMAQ
  #undef WBAR
  #undef WLGKM0
  #undef WVM4
  #undef WVM1
}

// ---------------------------------------------------------------- block reduction helper
__device__ __forceinline__ void lma_red2(float& s, float& sq){
  __shared__ float red[16];
  #pragma unroll
  for (int msk = 1; msk < 64; msk <<= 1){ s += __shfl_xor(s, msk); sq += __shfl_xor(sq, msk); }
  int w = threadIdx.x >> 6;
  if ((threadIdx.x & 63) == 0){ red[w] = s; red[8 + w] = sq; }
  __syncthreads();
  s  = red[0] + red[1] + red[2] + red[3];
  sq = red[8] + red[9] + red[10] + red[11];
}

// ---------------------------------------------------------------- generic LN (f32 in, bf16 or f32 out)
__global__ __launch_bounds__(256) void lma_ln(const float* __restrict__ in,
                                              const float* __restrict__ g, const float* __restrict__ bb,
                                              int D, unsigned short* __restrict__ obf, float* __restrict__ of32){
  int row = blockIdx.x, t = threadIdx.x;
  const float* x = in + (size_t)row * D;
  float s = 0.f, sq = 0.f;
  for (int d = t; d < D; d += 256){ float v = x[d]; s += v; sq += v * v; }
  lma_red2(s, sq);
  float mean = s / D;
  float var = sq / D - mean * mean;
  float rstd = rsqrtf(fmaxf(var, 0.f) + 1e-12f);
  if (obf) {
    for (int d = t; d < D; d += 256) obf[(size_t)row * D + d] = f2bf((x[d] - mean) * rstd * g[d] + bb[d]);
  } else {
    for (int d = t; d < D; d += 256) of32[(size_t)row * D + d] = (x[d] - mean) * rstd * g[d] + bb[d];
  }
}

// ---------------------------------------------------------------- branch-combined LN over T12b (bf16, D=512) -> LQ2 bf16
__global__ __launch_bounds__(256) void lma_ln2(const unsigned short* __restrict__ T12b,
                                               const float* __restrict__ fg, const float* __restrict__ fbb,
                                               const float* __restrict__ bg, const float* __restrict__ bbb,
                                               unsigned short* __restrict__ LQ2){
  int m = blockIdx.x, t = threadIdx.x;           // 0..2*M_-1
  int fb = (m >= M_);
  int idx = m - fb * M_;
  const float* g = fb ? bg : fg;
  const float* bb = fb ? bbb : fbb;
  const unsigned short* x = T12b + ((size_t)fb * PAD_ + idx) * 512;
  unsigned short* o = LQ2 + ((size_t)fb * PAD_ + idx) * 512;
  float v0 = bf2f(x[t]), v1 = bf2f(x[t + 256]);
  float s = v0 + v1, sq = v0*v0 + v1*v1;
  lma_red2(s, sq);
  float mean = s / 512.f;
  float var = sq / 512.f - mean * mean;
  float rstd = rsqrtf(fmaxf(var, 0.f) + 1e-12f);
  o[t]       = f2bf((v0 - mean) * rstd * g[t]       + bb[t]);
  o[t + 256] = f2bf((v1 - mean) * rstd * g[t + 256] + bb[t + 256]);
}

// ---------------------------------------------------------------- attn LN: LN(residual(hidden)+[pf,pb](bf16)) -> bf16 (M_ x 1024)
__global__ __launch_bounds__(256) void lma_attn_ln(const unsigned short* __restrict__ pf,
                                                   const unsigned short* __restrict__ pb,
                                                   const float* __restrict__ hidden,
                                                   const float* __restrict__ g, const float* __restrict__ bb,
                                                   unsigned short* __restrict__ out){
  int m = blockIdx.x, t = threadIdx.x;
  int b = m / S2_, s = m - b * S2_;
  const float* hf = hidden + ((size_t)s       * B_ + b) * 1024;
  const float* hb = hidden + ((size_t)(s + 2) * B_ + b) * 1024;
  float v[4]; float sum = 0.f, sq = 0.f;
  #pragma unroll
  for (int j = 0; j < 4; j++){
    int d = t + j * 256;
    float x = (d < 512) ? (bf2f(pf[(size_t)m * 512 + d]) + hf[d])
                        : (bf2f(pb[(size_t)m * 512 + (d - 512)]) + hb[d]);
    v[j] = x; sum += x; sq += x * x;
  }
  lma_red2(sum, sq);
  float mean = sum / 1024.f;
  float var = sq / 1024.f - mean * mean;
  float rstd = rsqrtf(fmaxf(var, 0.f) + 1e-12f);
  #pragma unroll
  for (int j = 0; j < 4; j++){
    int d = t + j * 256;
    out[(size_t)m * 1024 + d] = f2bf((v[j] - mean) * rstd * g[d] + bb[d]);
  }
}

// ---------------------------------------------------------------- combined flash attention v11: KVBLK=128 (2 k-tiles/iter)
// (round-16: restored best-measured version — 90.2us, VGPR 64, no scratch.
// Four attn restructurings falsified against it: v7 pipeline, v8 no-staging,
// v12 2-subtile @128cap (spill), v12b 2-subtile @256cap (no spill, still -10%).)
__global__ __launch_bounds__(256, 4) void lma_attn11(const unsigned short* __restrict__ Q2,
                                                     const unsigned short* __restrict__ KV2,
                                                     const unsigned short* __restrict__ VT2,
                                                     unsigned short* __restrict__ CT2,
                                                     const int* __restrict__ lens){
  __shared__ unsigned short Kl[2][64*64];
  __shared__ unsigned short Vl[2][64*64];
  __shared__ __align__(16) unsigned short Pl[4][16*64];

  const int tid = threadIdx.x;
  const int w = tid >> 6, lane = tid & 63, quad = lane >> 4, l16 = lane & 15;
  const int id = blockIdx.x;                 // 1024 blocks: [qt:4][h:3][b:3]
  const int qt = id >> 6, h = (id >> 3) & 7, b = id & 7;
  const int L2 = lens[b] - 2;
  const int q0wg = qt * 64;
  const int q0 = q0wg + w * 16;
  const int qg = q0 + l16;
  const int qload = (qg > S2_-1) ? (S2_-1) : qg;

  const size_t qbase  = ((size_t)b * S2_) * 512  + h * 64;
  const size_t kbase  = ((size_t)b * S2_) * 1024 + h * 64;
  const size_t vtbase = ((size_t)(b * 8 + h) * 64) * 1024;
  char* Pb = (char*)&Pl[w][0];

  const int lrow = lane >> 3;
  const int g0s  = (lane & 7) ^ lrow;
  const int x7   = l16 & 7;
  const int x7s  = x7 << 4;

  for (int fb = 0; fb < 2; fb++) {
    const int backward = fb;
    const unsigned short* Q  = Q2  + (size_t)fb * PAD_ * 512;
    const unsigned short* Kx = KV2 + (size_t)fb * PAD_ * 1024;
    const unsigned short* VT = VT2 + (size_t)fb * VTS_;
    unsigned short* CTX      = CT2 + (size_t)fb * PAD_ * 512;

    bf16x8 qf[2];
    {
      const unsigned short* qp = Q + qbase + (size_t)qload * 512 + quad * 8;
      qf[0] = *(const bf16x8*)(qp);
      qf[1] = *(const bf16x8*)(qp + 32);
    }

    float mi = -3e38f, li = 0.f;
    f32x4 ot[4];
    #pragma unroll
    for (int f = 0; f < 4; f++) ot[f] = f32x4{0.f,0.f,0.f,0.f};

    int klo = 0, khi = S2_ - 1;
    if (q0wg + 63 < L2) {
      if (!backward) khi = q0wg + 63;
      else { klo = q0wg; khi = L2 - 1; }
    }

    for (int kt0 = klo; kt0 <= khi; kt0 += 128) {
      const bool h2 = (kt0 + 64 <= khi);       // block-uniform
      const int span = h2 ? 127 : 63;

      #pragma unroll
      for (int c = 0; c < 2; c++) {
        int r = w*16 + c*8 + lrow;
        int kr = kt0 + r; if (kr > S2_-1) kr = S2_-1;
        glds16(Kx + kbase + (size_t)kr * 1024 + g0s * 8, &Kl[0][(w*16 + c*8) * 64]);
        glds16(VT + vtbase + (size_t)r * 1024 + kt0 + g0s * 8, &Vl[0][(w*16 + c*8) * 64]);
      }
      if (h2) {
        #pragma unroll
        for (int c = 0; c < 2; c++) {
          int r = w*16 + c*8 + lrow;
          int kr = kt0 + 64 + r; if (kr > S2_-1) kr = S2_-1;
          glds16(Kx + kbase + (size_t)kr * 1024 + g0s * 8, &Kl[1][(w*16 + c*8) * 64]);
          glds16(VT + vtbase + (size_t)r * 1024 + (kt0 + 64) + g0s * 8, &Vl[1][(w*16 + c*8) * 64]);
        }
      }
      __syncthreads();

      f32x4 st[8];
      {
        bf16x8 kf[4][2];
        #pragma unroll
        for (int sub = 0; sub < 4; sub++) {
          const unsigned short* kp = &Kl[0][(sub*16 + l16) * 64];
          kf[sub][0] = *(const bf16x8*)(kp + (( quad      ^ x7) * 8));
          kf[sub][1] = *(const bf16x8*)(kp + (((quad + 4) ^ x7) * 8));
        }
        __builtin_amdgcn_s_setprio(1);
        #pragma unroll
        for (int sub = 0; sub < 4; sub++) {
          f32x4 s = f32x4{0.f,0.f,0.f,0.f};
          s = __builtin_amdgcn_mfma_f32_16x16x32_bf16(kf[sub][0], qf[0], s, 0, 0, 0);
          s = __builtin_amdgcn_mfma_f32_16x16x32_bf16(kf[sub][1], qf[1], s, 0, 0, 0);
          st[sub] = s;
        }
        __builtin_amdgcn_s_setprio(0);
      }
      if (h2) {
        bf16x8 kf[4][2];
        #pragma unroll
        for (int sub = 0; sub < 4; sub++) {
          const unsigned short* kp = &Kl[1][(sub*16 + l16) * 64];
          kf[sub][0] = *(const bf16x8*)(kp + (( quad      ^ x7) * 8));
          kf[sub][1] = *(const bf16x8*)(kp + (((quad + 4) ^ x7) * 8));
        }
        __builtin_amdgcn_s_setprio(1);
        #pragma unroll
        for (int sub = 0; sub < 4; sub++) {
          f32x4 s = f32x4{0.f,0.f,0.f,0.f};
          s = __builtin_amdgcn_mfma_f32_16x16x32_bf16(kf[sub][0], qf[0], s, 0, 0, 0);
          s = __builtin_amdgcn_mfma_f32_16x16x32_bf16(kf[sub][1], qf[1], s, 0, 0, 0);
          st[4 + sub] = s;
        }
        __builtin_amdgcn_s_setprio(0);
      }

      {
        bool tail = (kt0 + span > S2_ - 1);
        bool full;
        if (!backward) full = !tail && ((kt0 + span <= q0) || (q0 >= L2));
        else           full = !tail && ((q0 >= L2) || ((kt0 >= q0 + 15) && (kt0 + span < L2)));
        if (!full) {
          #pragma unroll
          for (int sub = 0; sub < 4; sub++) {
            #pragma unroll
            for (int r = 0; r < 4; r++) {
              int kg = kt0 + sub*16 + quad*4 + r;
              bool ok;
              if (!backward) ok = (kg < S2_) && ((qg >= L2) || (kg <= qg));
              else           ok = (kg < S2_) && ((qg >= L2) || ((kg >= qg) && (kg < L2)));
              if (!ok) st[sub][r] = -3e38f;
            }
          }
          if (h2) {
            #pragma unroll
            for (int sub = 0; sub < 4; sub++) {
              #pragma unroll
              for (int r = 0; r < 4; r++) {
                int kg = kt0 + 64 + sub*16 + quad*4 + r;
                bool ok;
                if (!backward) ok = (kg < S2_) && ((qg >= L2) || (kg <= qg));
                else           ok = (kg < S2_) && ((qg >= L2) || ((kg >= qg) && (kg < L2)));
                if (!ok) st[4 + sub][r] = -3e38f;
              }
            }
          }
        }
      }

      float mx = -3e38f;
      #pragma unroll
      for (int sub = 0; sub < 4; sub++)
        #pragma unroll
        for (int r = 0; r < 4; r++) mx = fmaxf(mx, st[sub][r]);
      if (h2) {
        #pragma unroll
        for (int sub = 4; sub < 8; sub++)
          #pragma unroll
          for (int r = 0; r < 4; r++) mx = fmaxf(mx, st[sub][r]);
      }
      mx = fmaxf(mx, __shfl_xor(mx, 16));
      mx = fmaxf(mx, __shfl_xor(mx, 32));

      if (__any(mx > mi + 11.f)) {
        float mn = fmaxf(mi, mx);
        float al = fexp2(mi - mn);
        li *= al;
        #pragma unroll
        for (int f = 0; f < 4; f++)
          #pragma unroll
          for (int r = 0; r < 4; r++) ot[f][r] *= al;
        mi = mn;
      }

      float rs = 0.f;
      #pragma unroll
      for (int sub = 0; sub < 4; sub++)
        #pragma unroll
        for (int r = 0; r < 4; r++) {
          float p = fexp2(st[sub][r] - mi);
          st[sub][r] = p; rs += p;
        }
      if (h2) {
        #pragma unroll
        for (int sub = 4; sub < 8; sub++)
          #pragma unroll
          for (int r = 0; r < 4; r++) {
            float p = fexp2(st[sub][r] - mi);
            st[sub][r] = p; rs += p;
          }
      }
      rs += __shfl_xor(rs, 16);
      rs += __shfl_xor(rs, 32);
      li += rs;

      #pragma unroll
      for (int sub = 0; sub < 4; sub++) {
        u32x2 pk2;
        pk2[0] = cvtpk(st[sub][0], st[sub][1]);
        pk2[1] = cvtpk(st[sub][2], st[sub][3]);
        *(u32x2*)(Pb + (l16*128 + ((sub*32 + quad*8) ^ x7s))) = pk2;
      }
      {
        bf16x8 pfr0 = *(const bf16x8*)(Pb + (l16*128 + (( 0 + quad*16) ^ x7s)));
        bf16x8 pfr1 = *(const bf16x8*)(Pb + (l16*128 + ((64 + quad*16) ^ x7s)));
        bf16x8 vf[4][2];
        #pragma unroll
        for (int f = 0; f < 4; f++) {
          const unsigned short* vp = &Vl[0][(f*16 + l16) * 64];
          vf[f][0] = *(const bf16x8*)(vp + (( quad      ^ x7) * 8));
          vf[f][1] = *(const bf16x8*)(vp + (((quad + 4) ^ x7) * 8));
        }
        __builtin_amdgcn_s_setprio(1);
        #pragma unroll
        for (int f = 0; f < 4; f++) {
          ot[f] = __builtin_amdgcn_mfma_f32_16x16x32_bf16(vf[f][0], pfr0, ot[f], 0, 0, 0);
          ot[f] = __builtin_amdgcn_mfma_f32_16x16x32_bf16(vf[f][1], pfr1, ot[f], 0, 0, 0);
        }
        __builtin_amdgcn_s_setprio(0);
      }
      if (h2) {
        #pragma unroll
        for (int sub = 0; sub < 4; sub++) {
          u32x2 pk2;
          pk2[0] = cvtpk(st[4+sub][0], st[4+sub][1]);
          pk2[1] = cvtpk(st[4+sub][2], st[4+sub][3]);
          *(u32x2*)(Pb + (l16*128 + ((sub*32 + quad*8) ^ x7s))) = pk2;
        }
        bf16x8 pfr0 = *(const bf16x8*)(Pb + (l16*128 + (( 0 + quad*16) ^ x7s)));
        bf16x8 pfr1 = *(const bf16x8*)(Pb + (l16*128 + ((64 + quad*16) ^ x7s)));
        bf16x8 vf[4][2];
        #pragma unroll
        for (int f = 0; f < 4; f++) {
          const unsigned short* vp = &Vl[1][(f*16 + l16) * 64];
          vf[f][0] = *(const bf16x8*)(vp + (( quad      ^ x7) * 8));
          vf[f][1] = *(const bf16x8*)(vp + (((quad + 4) ^ x7) * 8));
        }
        __builtin_amdgcn_s_setprio(1);
        #pragma unroll
        for (int f = 0; f < 4; f++) {
          ot[f] = __builtin_amdgcn_mfma_f32_16x16x32_bf16(vf[f][0], pfr0, ot[f], 0, 0, 0);
          ot[f] = __builtin_amdgcn_mfma_f32_16x16x32_bf16(vf[f][1], pfr1, ot[f], 0, 0, 0);
        }
        __builtin_amdgcn_s_setprio(0);
      }
      __syncthreads();
    }

    if (qg < S2_) {
      float rcp = 1.f / li;
      #pragma unroll
      for (int f = 0; f < 4; f++) {
        ushort4 pk;
        pk.x = f2bf(ot[f][0] * rcp); pk.y = f2bf(ot[f][1] * rcp);
        pk.z = f2bf(ot[f][2] * rcp); pk.w = f2bf(ot[f][3] * rcp);
        *(ushort4*)&CTX[qbase + (size_t)qg * 512 + f*16 + quad*4] = pk;
      }
    }
  }
}

// ----------------------------------------------------------------
extern "C" void kernel_launch(void* const* d_in, const int* in_sizes, int n_in,
                              void* d_out, int out_size, void* d_ws, size_t ws_size,
                              hipStream_t stream)
{
  const float* hidden = (const float*)d_in[0];
  const int*   lens   = (const int*)d_in[1];
  const float* fw[14]; for (int i = 0; i < 14; i++) fw[i] = (const float*)d_in[2 + i];
  const float* bw[14]; for (int i = 0; i < 14; i++) bw[i] = (const float*)d_in[16 + i];
  const float* attn_g = (const float*)d_in[30];
  const float* attn_b = (const float*)d_in[31];
  const float* o_w1 = (const float*)d_in[32];
  const float* o_b1 = (const float*)d_in[33];
  const float* o_w2 = (const float*)d_in[34];
  const float* o_b2 = (const float*)d_in[35];
  const float* o_lng = (const float*)d_in[36];
  const float* o_lnb = (const float*)d_in[37];

  char* ws = (char*)d_ws;
  size_t off = 0;
  auto alloc = [&](size_t bytes)->char* {
    off = (off + 255) & ~(size_t)255;
    char* p = ws + off; off += bytes; return p;
  };

  unsigned short* fw1t = (unsigned short*)alloc((size_t)1024*1024*2);
  unsigned short* fw2t = (unsigned short*)alloc((size_t)512*1024*2);
  unsigned short* fqt  = (unsigned short*)alloc((size_t)512*512*2);
  unsigned short* fkvt = (unsigned short*)alloc((size_t)1024*512*2);  // [K(512 rows); V(512 rows)]
  unsigned short* fot  = (unsigned short*)alloc((size_t)512*512*2);
  unsigned short* bw1t = (unsigned short*)alloc((size_t)1024*1024*2);
  unsigned short* bw2t = (unsigned short*)alloc((size_t)512*1024*2);
  unsigned short* bqt  = (unsigned short*)alloc((size_t)512*512*2);
  unsigned short* bkvt = (unsigned short*)alloc((size_t)1024*512*2);
  unsigned short* bot  = (unsigned short*)alloc((size_t)512*512*2);
  unsigned short* ow1t = (unsigned short*)alloc((size_t)1024*1024*2);
  unsigned short* ow2t = (unsigned short*)alloc((size_t)1024*1024*2);
  float*          biasKV = (float*)alloc(2048*4);

  unsigned short* Xb   = (unsigned short*)alloc((size_t)M_*1024*2);
  unsigned short* big1 = (unsigned short*)alloc((size_t)2*PAD_*1024*2);
  float*          big2 = (float*)alloc((size_t)2*PAD_*512*4);
  unsigned short* LQCT = (unsigned short*)alloc((size_t)2*PAD_*512*2);
  unsigned short* Q2   = (unsigned short*)alloc((size_t)2*PAD_*512*2);

  unsigned short* H12 = big1, *KV2 = big1, *H1o = big1;
  // big2 partitions: [0 .. 2*VTS_) = T12b (bf16) then VT2 (bf16);
  //                  [2*VTS_ .. 4*VTS_) = P2b (bf16 out-proj). Exactly fills big2.
  unsigned short* T12b = (unsigned short*)big2;
  unsigned short* VT2  = (unsigned short*)big2;
  unsigned short* P2b  = (unsigned short*)big2 + 2*VTS_;
  unsigned short* LQ2 = LQCT, *CT2 = LQCT;

  lma_prep_x<<<M_, 256, 0, stream>>>(hidden, Xb);

  {
    TPack tp;
    const float* srcs[14] = { fw[0], fw[2], fw[6], fw[8], fw[10], fw[12],
                              bw[0], bw[2], bw[6], bw[8], bw[10], bw[12],
                              o_w1, o_w2 };
    unsigned short* dsts[14] = { fw1t, fw2t, fqt, fkvt, fkvt + (size_t)512*512, fot,
                                 bw1t, bw2t, bqt, bkvt, bkvt + (size_t)512*512, bot,
                                 ow1t, ow2t };
    int Ks[14] = {1024,1024,512,512,512,512, 1024,1024,512,512,512,512, 1024,1024};
    int Ns[14] = {1024, 512,512,512,512,512, 1024, 512,512,512,512,512, 1024,1024};
    for (int i = 0; i < 14; i++){ tp.src[i]=srcs[i]; tp.dst[i]=dsts[i]; tp.K[i]=Ks[i]; tp.N[i]=Ns[i]; }
    lma_transpose_all<<<dim3(32, 32, 14), 256, 0, stream>>>(tp);
  }
  lma_biascat<<<8, 256, 0, stream>>>(fw[9], fw[11], bw[9], bw[11], biasKV);

  auto G8 = [&](const unsigned short* A, int lda,
                const unsigned short* B0, const unsigned short* B1,
                const float* b0, const float* b1,
                unsigned short* C, int ldc, int M, int N, int K, int mode, int amap){
    int nmt = M / 256;
    lma_gemm8<<<dim3(nmt * (N/256)), 512, 0, stream>>>(A, lda, B0, B1, b0, b1, C, ldc, M, N, K, mode, amap, nmt);
  };
  auto G8W = [&](const unsigned short* A, int lda,
                 const unsigned short* B0, const unsigned short* B1,
                 const float* b0, const float* b1,
                 void* C, int ldc, int M, int N, int K, int mode){
    int nmt = (M + 127) / 128;
    lma_gemm8w<<<dim3(nmt * (N/256)), 512, 0, stream>>>(A, lda, B0, B1, b0, b1, C, ldc, M, N, K, mode, nmt);
  };

  // both-branch FFN + LN + projections (rows<8192 = forward, >=8192 = backward)
  G8(Xb, 1024, fw1t, bw1t, fw[1], bw[1], H12, 1024, 2*PAD_, 1024, 1024, 2, 1);   // FFN1+gelu (256^2 8-phase)
  G8W(H12, 1024, fw2t, bw2t, fw[3], bw[3], T12b, 512, 2*PAD_, 512, 1024, 0);     // FFN2 -> bf16 (128x256 8-phase)
  lma_ln2<<<2*M_, 256, 0, stream>>>(T12b, fw[4], fw[5], bw[4], bw[5], LQ2);
  G8W(LQ2, 512, fqt, bqt, fw[7], bw[7], Q2, 512, 2*PAD_, 512, 512, 1);           // Q (x0.125*log2e)
  G8(Xb, 1024, fkvt, bkvt, biasKV, biasKV + 1024, KV2, 1024, 2*PAD_, 1024, 512, 0, 2); // K|V (256^2 8-phase)
  lma_vt2<<<dim3(32, 16, 16), 256, 0, stream>>>(KV2, VT2);

  lma_attn11<<<dim3(1024), 256, 0, stream>>>(Q2, KV2, VT2, CT2, lens);

  G8W(CT2, 512, fot, bot, fw[13], bw[13], P2b, 512, 2*PAD_, 512, 512, 0);        // out proj -> bf16

  lma_attn_ln<<<M_, 256, 0, stream>>>(P2b, P2b + (size_t)PAD_*512, hidden, attn_g, attn_b, Xb);

  G8W(Xb, 1024, ow1t, ow1t, o_b1, o_b1, H1o, 1024, M_, 1024, 1024, 2);           // out FFN1+gelu
  G8W(H1o, 1024, ow2t, ow2t, o_b2, o_b2, (float*)d_out, 1024, M_, 1024, 1024, 4); // out FFN2 -> d_out (remapped)
  lma_ln<<<M_, 256, 0, stream>>>((float*)d_out, o_lng, o_lnb, 1024, nullptr, (float*)d_out);
}

// Round 17
// 512.180 us; speedup vs baseline: 1.0345x; 1.0105x over previous
//
#include <hip/hip_runtime.h>
#include <cmath>

#define S_ 1024
#define B_ 8
#define H_ 512
#define S2_ 1022
#define M_ (B_*S2_)     // 8176
#define PAD_ 8192
#define VTS_ ((size_t)8*8*64*1024)   // VT per-branch stride (4194304 shorts)

typedef __attribute__((ext_vector_type(8))) short bf16x8;
typedef __attribute__((ext_vector_type(4))) float f32x4;
typedef __attribute__((ext_vector_type(4))) unsigned int u32x4;
typedef __attribute__((ext_vector_type(2))) unsigned int u32x2;
typedef __attribute__((ext_vector_type(4))) unsigned short u16x4;

__device__ __forceinline__ unsigned short f2bf(float f){
  unsigned int u = __float_as_uint(f);
  return (unsigned short)((u + 0x7fffu + ((u>>16)&1u)) >> 16);
}
__device__ __forceinline__ float bf2f(unsigned short u){
  return __uint_as_float((unsigned int)u << 16);
}
// tanh-approx gelu: x*sigmoid(2*(c1 x + c2 x^3)); |err vs erf-gelu| < ~3e-4
__device__ __forceinline__ float fgelu(float x){
  float u = x * (0.7978845608f + 0.0356774081f * x * x);
  return x / (1.f + __expf(-2.f * u));
}
// raw 2^x (v_exp_f32 is natively base-2)
__device__ __forceinline__ float fexp2(float x){
  float r; asm("v_exp_f32 %0, %1" : "=v"(r) : "v"(x)); return r;
}
// hardware packed f32->bf16 (RNE), lo -> bits[15:0], hi -> bits[31:16]
__device__ __forceinline__ unsigned int cvtpk(float lo, float hi){
  unsigned int r; asm("v_cvt_pk_bf16_f32 %0, %1, %2" : "=v"(r) : "v"(lo), "v"(hi)); return r;
}

__device__ __forceinline__ void glds16(const void* g, void* l){
  __builtin_amdgcn_global_load_lds((const __attribute__((address_space(1))) unsigned int*)g,
                                   (__attribute__((address_space(3))) unsigned int*)l, 16, 0, 0);
}
#define SB() __builtin_amdgcn_sched_barrier(0)

// ---------------------------------------------------------------- prep: X = [f[:-2], bk[2:]] bf16 (M_ x 1024)
__global__ __launch_bounds__(256) void lma_prep_x(const float* __restrict__ hidden,
                                                  unsigned short* __restrict__ Xb){
  int m = blockIdx.x; int dq = threadIdx.x * 4;
  int b = m / S2_, s = m - b * S2_;
  int srow = (dq < 512) ? s : (s + 2);
  const float* src = hidden + ((size_t)srow * B_ + b) * 1024 + dq;
  f32x4 v = *(const f32x4*)src;
  union { u32x2 u; unsigned short s4[4]; } pk;
  #pragma unroll
  for (int j = 0; j < 4; j++) pk.s4[j] = f2bf(v[j]);
  *(u32x2*)&Xb[(size_t)m * 1024 + dq] = pk.u;
}

// ---------------------------------------------------------------- batched weight transpose+cast
struct TPack {
  const float* src[14];
  unsigned short* dst[14];
  int K[14];
  int N[14];
};
__global__ __launch_bounds__(256) void lma_transpose_all(TPack p){
  int idx = blockIdx.z;
  int K = p.K[idx], N = p.N[idx];
  int kb = blockIdx.x * 32, nb = blockIdx.y * 32;
  if (kb >= K || nb >= N) return;
  const float* W = p.src[idx];
  unsigned short* WT = p.dst[idx];
  __shared__ float t[32][33];
  int tx = threadIdx.x & 31, ty = threadIdx.x >> 5;
  #pragma unroll
  for (int i = ty; i < 32; i += 8) t[i][tx] = W[(size_t)(kb + i) * N + nb + tx];
  __syncthreads();
  #pragma unroll
  for (int i = ty; i < 32; i += 8) WT[(size_t)(nb + i) * K + kb + tx] = f2bf(t[tx][i]);
}

// ---------------------------------------------------------------- concat K/V biases
__global__ __launch_bounds__(256) void lma_biascat(const float* __restrict__ fk, const float* __restrict__ fv,
                                                   const float* __restrict__ bk, const float* __restrict__ bv,
                                                   float* __restrict__ out){
  int i = blockIdx.x * 256 + threadIdx.x;     // 0..2047
  int fb = i >> 10, col = i & 1023;
  const float* s = (col < 512) ? (fb ? bk : fk) : (fb ? bv : fv);
  out[i] = s[col & 511];
}

// ---------------------------------------------------------------- V (in KV2, cols 512..1023) -> VT2[fb][b][h][d][s pad 1024]
// Pad cols s in [S2_,1024) ZEROED (aliased buffer may hold bf16-NaN bit patterns).
__global__ __launch_bounds__(256) void lma_vt2(const unsigned short* __restrict__ KV2,
                                               unsigned short* __restrict__ VT2){
  __shared__ unsigned short t[32][34];
  int s0 = blockIdx.x * 32, c0 = blockIdx.y * 32;
  int z = blockIdx.z, fb = z >> 3, b = z & 7;
  const unsigned short* V = KV2 + (size_t)fb * PAD_ * 1024 + 512;
  unsigned short* VT = VT2 + (size_t)fb * VTS_;
  int tx = threadIdx.x & 31, ty = threadIdx.x >> 5;
  #pragma unroll
  for (int i = ty; i < 32; i += 8){
    int s = s0 + i; if (s > S2_-1) s = S2_-1;
    t[i][tx] = V[((size_t)b * S2_ + s) * 1024 + c0 + tx];
  }
  __syncthreads();
  int s = s0 + tx;
  #pragma unroll
  for (int i = ty; i < 32; i += 8){
    int c = c0 + i, h = c >> 6, d = c & 63;
    VT[(((size_t)b * 8 + h) * 64 + d) * 1024 + s] = (s < S2_) ? t[tx][i] : (unsigned short)0;
  }
}

// ---------------------------------------------------------------- 128^2 2-phase GEMM (kept as fallback; no call sites)
__global__ __launch_bounds__(256) void lma_gemm2(
    const unsigned short* __restrict__ A, int lda,
    const unsigned short* __restrict__ Bt0, const unsigned short* __restrict__ Bt1,
    const float* __restrict__ bias0, const float* __restrict__ bias1,
    void* __restrict__ Cout, int ldc,
    int M, int N, int K, int mode, int amap, int nmt)
{
  __shared__ unsigned short Al[128*32];
  __shared__ unsigned short Bl[128*32];
  const int tid = threadIdx.x;
  const int w = tid >> 6, lane = tid & 63, quad = lane >> 4, l16 = lane & 15;
  const int mt = blockIdx.x % nmt, nt = blockIdx.x / nmt;
  const int m0 = mt * 128, n0 = nt * 128;
  const int brch = m0 >> 13;
  const unsigned short* Bt = brch ? Bt1 : Bt0;
  const float* bias = brch ? bias1 : bias0;
  const int coloff = (amap == 2 && brch) ? 512 : 0;
  const int wm = (w >> 1) * 64, wn = (w & 1) * 64;

  f32x4 acc[4][4];
  #pragma unroll
  for (int i = 0; i < 4; i++)
    #pragma unroll
    for (int f = 0; f < 4; f++) acc[i][f] = f32x4{0.f,0.f,0.f,0.f};

  const int srow = lane >> 2;
  const int spc  = (((lane & 3) ^ ((lane >> 3) & 3))) * 8;
  const int rswz = (l16 >> 1) & 3;

  for (int k0 = 0; k0 < K; k0 += 32) {
    #pragma unroll
    for (int c = 0; c < 2; c++) {
      int ra = w*32 + c*16 + srow;
      int ga = m0 + ra;
      int ar;
      if (amap == 0) { ar = (ga > M-1) ? (M-1) : ga; }
      else { ar = ga & (PAD_-1); if (ar > M_-1) ar = M_-1; }
      glds16(A + (size_t)ar * lda + coloff + k0 + spc, &Al[(w*32 + c*16) * 32]);
      int gb = n0 + ra; if (gb > N-1) gb = N-1;
      glds16(Bt + (size_t)gb * K + k0 + spc, &Bl[(w*32 + c*16) * 32]);
    }
    __syncthreads();
    bf16x8 af[4], bfr[4];
    #pragma unroll
    for (int i = 0; i < 4; i++) af[i]  = *(const bf16x8*)&Al[(wm + i*16 + l16)*32 + ((quad ^ rswz) * 8)];
    #pragma unroll
    for (int f = 0; f < 4; f++) bfr[f] = *(const bf16x8*)&Bl[(wn + f*16 + l16)*32 + ((quad ^ rswz) * 8)];
    #pragma unroll
    for (int i = 0; i < 4; i++)
      #pragma unroll
      for (int f = 0; f < 4; f++)
        acc[i][f] = __builtin_amdgcn_mfma_f32_16x16x32_bf16(af[i], bfr[f], acc[i][f], 0, 0, 0);
    __syncthreads();
  }

  float bv[4];
  #pragma unroll
  for (int f = 0; f < 4; f++) bv[f] = bias ? bias[n0 + wn + f*16 + l16] : 0.f;
  const int col0 = n0 + wn + l16;
  #pragma unroll
  for (int i = 0; i < 4; i++) {
    #pragma unroll
    for (int r = 0; r < 4; r++) {
      int row = m0 + wm + i*16 + quad*4 + r;
      if (row < M) {
        #pragma unroll
        for (int f = 0; f < 4; f++) {
          float v = acc[i][f][r] + bv[f];
          if (mode == 2) v = fgelu(v);
          else if (mode == 1) v *= 0.18033688011112042f;
          if (mode <= 2) ((unsigned short*)Cout)[(size_t)row * ldc + col0 + f*16] = f2bf(v);
          else if (mode == 3) ((float*)Cout)[(size_t)row * ldc + col0 + f*16] = v;
          else {
            int sr = row % S2_, bb2 = row / S2_;
            ((float*)Cout)[((size_t)sr * B_ + bb2) * ldc + col0 + f*16] = v;
          }
        }
      }
    }
  }
}

// ---------------------------------------------------------------- 256^2 8-phase GEMM v4 (T2+T3+T4+T5; fence diet, r12-measured win)
__global__ __launch_bounds__(512, 2) void lma_gemm8(
    const unsigned short* __restrict__ A, int lda,
    const unsigned short* __restrict__ Bt0, const unsigned short* __restrict__ Bt1,
    const float* __restrict__ bias0, const float* __restrict__ bias1,
    unsigned short* __restrict__ Cout, int ldc,
    int M, int N, int K, int mode, int amap, int nmt)
{
  __shared__ unsigned short Ls[2][2][256*64];   // [buf][0=A,1=B][row*64+k]
  const int tid = threadIdx.x;
  const int w = tid >> 6, lane = tid & 63, quad = lane >> 4, l16 = lane & 15;
  const int mt = blockIdx.x % nmt, nt = blockIdx.x / nmt;
  const int m0 = mt * 256, n0 = nt * 256;
  const int brch = m0 >> 13;
  const unsigned short* Bt = brch ? Bt1 : Bt0;
  const float* bias = brch ? bias1 : bias0;
  const int coloff = (amap == 2 && brch) ? 512 : 0;
  const int wm = (w >> 2) * 128, wn = (w & 3) * 64;

  f32x4 acc[8][4];
  #pragma unroll
  for (int i = 0; i < 8; i++)
    #pragma unroll
    for (int f = 0; f < 4; f++) acc[i][f] = f32x4{0.f,0.f,0.f,0.f};

  const int lrow8 = lane >> 3;
  const int lkb   = lane & 7;
  const int NT = K >> 6;

  const unsigned short* aP[2][2]; const unsigned short* bP[2][2];
  int aD[2][2], bD[2][2];
  #pragma unroll
  for (int hf = 0; hf < 2; hf++)
    #pragma unroll
    for (int c = 0; c < 2; c++) {
      int rtA = (w>>2)*128 + hf*64 + ((w&3)*2 + c)*8 + lrow8;
      int kbA = lkb ^ (rtA & 7);
      int ga = m0 + rtA;
      int ar;
      if (amap == 0) { ar = (ga > M-1) ? (M-1) : ga; }
      else { ar = ga & (PAD_-1); if (ar > M_-1) ar = M_-1; }
      aP[hf][c] = A + (size_t)ar * lda + coloff + kbA*8;
      aD[hf][c] = ((w>>2)*128 + hf*64 + ((w&3)*2 + c)*8) * 64;
      int rtB = (w>>1)*64 + hf*32 + ((w&1)*2 + c)*8 + lrow8;
      int kbB = lkb ^ (rtB & 7);
      int gb = n0 + rtB; if (gb > N-1) gb = N-1;
      bP[hf][c] = Bt + (size_t)gb * K + kbB*8;
      bD[hf][c] = ((w>>1)*64 + hf*32 + ((w&1)*2 + c)*8) * 64;
    }

  bf16x8 af[4][2], bf[2][2];

  #define STA(buf, hf, kt) { _Pragma("unroll") for (int c = 0; c < 2; c++) \
      glds16(aP[hf][c] + (size_t)(kt)*64, &Ls[buf][0][aD[hf][c]]); }
  #define STB(buf, hf, kt) { _Pragma("unroll") for (int c = 0; c < 2; c++) \
      glds16(bP[hf][c] + (size_t)(kt)*64, &Ls[buf][1][bD[hf][c]]); }
  #define LDA8(buf, mq) { _Pragma("unroll") for (int j = 0; j < 4; j++){ \
      int rt = wm + (mq)*64 + j*16 + l16; \
      const unsigned short* base = &Ls[buf][0][rt*64]; \
      int f_ = rt & 7; \
      af[j][0] = *(const bf16x8*)(base + ((    quad) ^ f_)*8); \
      af[j][1] = *(const bf16x8*)(base + ((4 + quad) ^ f_)*8); } }
  #define LDB8(buf, nq) { _Pragma("unroll") for (int j = 0; j < 2; j++){ \
      int rt = wn + (nq)*32 + j*16 + l16; \
      const unsigned short* base = &Ls[buf][1][rt*64]; \
      int f_ = rt & 7; \
      bf[j][0] = *(const bf16x8*)(base + ((    quad) ^ f_)*8); \
      bf[j][1] = *(const bf16x8*)(base + ((4 + quad) ^ f_)*8); } }
  #define MFMAQ(mq, nq) { __builtin_amdgcn_s_setprio(1); \
      _Pragma("unroll") for (int j = 0; j < 4; j++) \
        _Pragma("unroll") for (int j2 = 0; j2 < 2; j2++){ \
          acc[(mq)*4+j][(nq)*2+j2] = __builtin_amdgcn_mfma_f32_16x16x32_bf16(af[j][0], bf[j2][0], acc[(mq)*4+j][(nq)*2+j2], 0, 0, 0); \
          acc[(mq)*4+j][(nq)*2+j2] = __builtin_amdgcn_mfma_f32_16x16x32_bf16(af[j][1], bf[j2][1], acc[(mq)*4+j][(nq)*2+j2], 0, 0, 0); } \
      __builtin_amdgcn_s_setprio(0); }
  #define BAR()   { __builtin_amdgcn_s_barrier(); }
  #define LGKM0() { asm volatile("s_waitcnt lgkmcnt(0)" ::: "memory"); SB(); }
  #define VM6()   { asm volatile("s_waitcnt vmcnt(6)"   ::: "memory"); }
  #define VM2()   { asm volatile("s_waitcnt vmcnt(2)"   ::: "memory"); }

  STA(0, 0, 0); STB(0, 0, 0); STB(0, 1, 0); STA(0, 1, 0);
  STA(1, 0, 1);
  asm volatile("s_waitcnt vmcnt(2)" ::: "memory");
  BAR();

  const int NI = NT >> 1;
  for (int i = 0; i < NI; i++) {
    const int tb  = 2*i + 1;
    int ta2 = 2*i + 2; if (ta2 > NT-1) ta2 = NT-1;
    int tb2 = 2*i + 3; if (tb2 > NT-1) tb2 = NT-1;

    LDA8(0, 0); LDB8(0, 0); STB(1, 0, tb);
    BAR(); LGKM0(); MFMAQ(0, 0); BAR();
    LDB8(0, 1); STB(1, 1, tb);
    BAR(); LGKM0(); MFMAQ(0, 1); BAR();
    LDA8(0, 1); STA(1, 1, tb);
    BAR(); LGKM0(); MFMAQ(1, 1); BAR();
    LDB8(0, 0); STA(0, 0, ta2);
    BAR(); LGKM0(); MFMAQ(1, 0); VM6(); BAR();
    LDA8(1, 0); LDB8(1, 0); STB(0, 1, ta2);
    BAR(); LGKM0(); MFMAQ(0, 0); VM6(); BAR();
    LDB8(1, 1); STA(0, 1, ta2);
    BAR(); LGKM0(); MFMAQ(0, 1); VM6(); BAR();
    LDA8(1, 1); STB(0, 0, ta2);
    BAR(); LGKM0(); MFMAQ(1, 1); BAR();
    LDB8(1, 0); STA(1, 0, tb2);
    BAR(); LGKM0(); MFMAQ(1, 0); VM2(); BAR();
  }
  asm volatile("s_waitcnt vmcnt(0)" ::: "memory");

  float bv[4];
  #pragma unroll
  for (int f = 0; f < 4; f++) bv[f] = bias ? bias[n0 + wn + f*16 + l16] : 0.f;
  const int col0 = n0 + wn + l16;
  #pragma unroll
  for (int i2 = 0; i2 < 8; i2++) {
    #pragma unroll
    for (int r = 0; r < 4; r++) {
      int row = m0 + wm + i2*16 + quad*4 + r;
      if (row < M) {
        #pragma unroll
        for (int f = 0; f < 4; f++) {
          float v = acc[i2][f][r] + bv[f];
          if (mode == 2) v = fgelu(v);
          Cout[(size_t)row * ldc + col0 + f*16] = f2bf(v);
        }
      }
    }
  }
  #undef STA
  #undef STB
  #undef LDA8
  #undef LDB8
  #undef MFMAQ
  #undef BAR
  #undef LGKM0
  #undef VM6
  #undef VM2
}

// ---------------------------------------------------------------- 128x256 8-phase GEMM (gemm8w) v2 — fence diet (r12-measured win)
__global__ __launch_bounds__(512, 2) void lma_gemm8w(
    const unsigned short* __restrict__ A, int lda,
    const unsigned short* __restrict__ Bt0, const unsigned short* __restrict__ Bt1,
    const float* __restrict__ bias0, const float* __restrict__ bias1,
    void* __restrict__ Cout, int ldc,
    int M, int N, int K, int mode, int nmt)
{
  __shared__ unsigned short LsA[2][128*64];   // 2 x 16KB
  __shared__ unsigned short LsB[2][256*64];   // 2 x 32KB
  const int tid = threadIdx.x;
  const int w = tid >> 6, lane = tid & 63, quad = lane >> 4, l16 = lane & 15;
  const int mt = blockIdx.x % nmt, nt = blockIdx.x / nmt;
  const int m0 = mt * 128, n0 = nt * 256;
  const int brch = m0 >> 13;
  const unsigned short* Bt = brch ? Bt1 : Bt0;
  const float* bias = brch ? bias1 : bias0;
  const int wm = (w >> 2) * 64, wn = (w & 3) * 64;

  f32x4 acc[4][4];
  #pragma unroll
  for (int i = 0; i < 4; i++)
    #pragma unroll
    for (int f = 0; f < 4; f++) acc[i][f] = f32x4{0.f,0.f,0.f,0.f};

  const int lrow8 = lane >> 3;
  const int lkb   = lane & 7;
  const int NT = K >> 6;

  const unsigned short* aP[2]; int aD[2];
  const unsigned short* bP[2][2]; int bD[2][2];
  #pragma unroll
  for (int hf = 0; hf < 2; hf++) {
    int rtA = hf*64 + w*8 + lrow8;
    int kbA = lkb ^ (rtA & 7);
    int ga = m0 + rtA; if (ga > M-1) ga = M-1;
    aP[hf] = A + (size_t)ga * lda + kbA*8;
    aD[hf] = (hf*64 + w*8) * 64;
    #pragma unroll
    for (int c = 0; c < 2; c++) {
      int rtB = hf*128 + (w*2 + c)*8 + lrow8;
      int kbB = lkb ^ (rtB & 7);
      int gb = n0 + rtB; if (gb > N-1) gb = N-1;
      bP[hf][c] = Bt + (size_t)gb * K + kbB*8;
      bD[hf][c] = (hf*128 + (w*2 + c)*8) * 64;
    }
  }

  bf16x8 af[2][2], bf[2][2];

  #define WSTA(buf, hf, kt) { glds16(aP[hf] + (size_t)(kt)*64, &LsA[buf][aD[hf]]); }
  #define WSTB(buf, hf, kt) { _Pragma("unroll") for (int c = 0; c < 2; c++) \
      glds16(bP[hf][c] + (size_t)(kt)*64, &LsB[buf][bD[hf][c]]); }
  #define WLDA(buf, mq) { _Pragma("unroll") for (int j = 0; j < 2; j++){ \
      int rt = wm + (mq)*32 + j*16 + l16; \
      const unsigned short* base = &LsA[buf][rt*64]; \
      int f_ = rt & 7; \
      af[j][0] = *(const bf16x8*)(base + ((    quad) ^ f_)*8); \
      af[j][1] = *(const bf16x8*)(base + ((4 + quad) ^ f_)*8); } }
  #define WLDB(buf, nq) { _Pragma("unroll") for (int j = 0; j < 2; j++){ \
      int rt = wn + (nq)*32 + j*16 + l16; \
      const unsigned short* base = &LsB[buf][rt*64]; \
      int f_ = rt & 7; \
      bf[j][0] = *(const bf16x8*)(base + ((    quad) ^ f_)*8); \
      bf[j][1] = *(const bf16x8*)(base + ((4 + quad) ^ f_)*8); } }
  #define WMFMAQ(mq, nq) { __builtin_amdgcn_s_setprio(1); \
      _Pragma("unroll") for (int j = 0; j < 2; j++) \
        _Pragma("unroll") for (int j2 = 0; j2 < 2; j2++){ \
          acc[(mq)*2+j][(nq)*2+j2] = __builtin_amdgcn_mfma_f32_16x16x32_bf16(af[j][0], bf[j2][0], acc[(mq)*2+j][(nq)*2+j2], 0, 0, 0); \
          acc[(mq)*2+j][(nq)*2+j2] = __builtin_amdgcn_mfma_f32_16x16x32_bf16(af[j][1], bf[j2][1], acc[(mq)*2+j][(nq)*2+j2], 0, 0, 0); } \
      __builtin_amdgcn_s_setprio(0); }
  #define WBAR()   { __builtin_amdgcn_s_barrier(); }
  #define WLGKM0() { asm volatile("s_waitcnt lgkmcnt(0)" ::: "memory"); SB(); }
  #define WVM4()   { asm volatile("s_waitcnt vmcnt(4)"   ::: "memory"); }
  #define WVM1()   { asm volatile("s_waitcnt vmcnt(1)"   ::: "memory"); }

  WSTA(0, 0, 0); WSTB(0, 0, 0); WSTB(0, 1, 0); WSTA(0, 1, 0);
  WSTA(1, 0, 1);
  WVM1(); WBAR();

  const int NI = NT >> 1;
  for (int i = 0; i < NI; i++) {
    const int tb  = 2*i + 1;
    int ta2 = 2*i + 2; if (ta2 > NT-1) ta2 = NT-1;
    int tb2 = 2*i + 3; if (tb2 > NT-1) tb2 = NT-1;

    WLDA(0, 0); WLDB(0, 0); WSTB(1, 0, tb);
    WBAR(); WLGKM0(); WMFMAQ(0, 0); WBAR();
    WLDB(0, 1); WSTB(1, 1, tb);
    WBAR(); WLGKM0(); WMFMAQ(0, 1); WBAR();
    WLDA(0, 1); WSTA(1, 1, tb);
    WBAR(); WLGKM0(); WMFMAQ(1, 1); WBAR();
    WLDB(0, 0); WSTA(0, 0, ta2);
    WBAR(); WLGKM0(); WMFMAQ(1, 0); WVM4(); WBAR();
    WLDA(1, 0); WLDB(1, 0); WSTB(0, 1, ta2);
    WBAR(); WLGKM0(); WMFMAQ(0, 0); WVM4(); WBAR();
    WLDB(1, 1); WSTA(0, 1, ta2);
    WBAR(); WLGKM0(); WMFMAQ(0, 1); WVM4(); WBAR();
    WLDA(1, 1); WSTB(0, 0, ta2);
    WBAR(); WLGKM0(); WMFMAQ(1, 1); WBAR();
    WLDB(1, 0); WSTA(1, 0, tb2);
    WBAR(); WLGKM0(); WMFMAQ(1, 0); WVM1(); WBAR();
  }
  asm volatile("s_waitcnt vmcnt(0)" ::: "memory");

  float bv[4];
  #pragma unroll
  for (int f = 0; f < 4; f++) bv[f] = bias ? bias[n0 + wn + f*16 + l16] : 0.f;
  const int col0 = n0 + wn + l16;
  #pragma unroll
  for (int i2 = 0; i2 < 4; i2++) {
    #pragma unroll
    for (int r = 0; r < 4; r++) {
      int row = m0 + wm + i2*16 + quad*4 + r;
      if (row < M) {
        #pragma unroll
        for (int f = 0; f < 4; f++) {
          float v = acc[i2][f][r] + bv[f];
          if (mode == 2) v = fgelu(v);
          else if (mode == 1) v *= 0.18033688011112042f;   // 0.125 * log2(e)
          if (mode <= 2) ((unsigned short*)Cout)[(size_t)row * ldc + col0 + f*16] = f2bf(v);
          else if (mode == 3) ((float*)Cout)[(size_t)row * ldc + col0 + f*16] = v;
          else {
            int sr = row % S2_, bb2 = row / S2_;
            ((float*)Cout)[((size_t)sr * B_ + bb2) * ldc + col0 + f*16] = v;
          }
        }
      }
    }
  }
  #undef WSTA
  #undef WSTB
  #undef WLDA
  #undef WLDB
  #undef WMFMAQ
  #undef WBAR
  #undef WLGKM0
  #undef WVM4
  #undef WVM1
}

// ---------------------------------------------------------------- block reduction helper
__device__ __forceinline__ void lma_red2(float& s, float& sq){
  __shared__ float red[16];
  #pragma unroll
  for (int msk = 1; msk < 64; msk <<= 1){ s += __shfl_xor(s, msk); sq += __shfl_xor(sq, msk); }
  int w = threadIdx.x >> 6;
  if ((threadIdx.x & 63) == 0){ red[w] = s; red[8 + w] = sq; }
  __syncthreads();
  s  = red[0] + red[1] + red[2] + red[3];
  sq = red[8] + red[9] + red[10] + red[11];
}

// ---------------------------------------------------------------- final LN (D=1024 f32 in, f32 out) — round-17: f32x4 vectorized
// (G13: scalar 4B/lane loads ~2x slower on memory-bound kernels; row cached in
// registers so the old second-pass re-read is eliminated entirely.)
__global__ __launch_bounds__(256) void lma_ln(const float* __restrict__ in,
                                              const float* __restrict__ g, const float* __restrict__ bb,
                                              int D, unsigned short* __restrict__ obf, float* __restrict__ of32){
  int row = blockIdx.x, t = threadIdx.x;        // D == 1024, 256 thr x 4 contiguous
  const float* x = in + (size_t)row * D;
  f32x4 v = *(const f32x4*)&x[t * 4];
  float s  = v[0] + v[1] + v[2] + v[3];
  float sq = v[0]*v[0] + v[1]*v[1] + v[2]*v[2] + v[3]*v[3];
  lma_red2(s, sq);
  float mean = s / D;
  float var = sq / D - mean * mean;
  float rstd = rsqrtf(fmaxf(var, 0.f) + 1e-12f);
  f32x4 gv = *(const f32x4*)&g[t * 4];
  f32x4 bv = *(const f32x4*)&bb[t * 4];
  f32x4 o;
  #pragma unroll
  for (int j = 0; j < 4; j++) o[j] = (v[j] - mean) * rstd * gv[j] + bv[j];
  if (obf) {
    u32x2 pk; pk[0] = cvtpk(o[0], o[1]); pk[1] = cvtpk(o[2], o[3]);
    *(u32x2*)&obf[(size_t)row * D + t * 4] = pk;
  } else {
    *(f32x4*)&of32[(size_t)row * D + t * 4] = o;
  }
}

// ---------------------------------------------------------------- branch-combined LN over T12b (bf16, D=512) -> LQ2 bf16
// round-17: packed u32 (2xbf16) loads + cvtpk store (was 2x scalar 2B loads/stores)
__global__ __launch_bounds__(256) void lma_ln2(const unsigned short* __restrict__ T12b,
                                               const float* __restrict__ fg, const float* __restrict__ fbb,
                                               const float* __restrict__ bg, const float* __restrict__ bbb,
                                               unsigned short* __restrict__ LQ2){
  int m = blockIdx.x, t = threadIdx.x;           // 0..2*M_-1
  int fb = (m >= M_);
  int idx = m - fb * M_;
  const float* g = fb ? bg : fg;
  const float* bb = fb ? bbb : fbb;
  const unsigned short* x = T12b + ((size_t)fb * PAD_ + idx) * 512;
  unsigned short* o = LQ2 + ((size_t)fb * PAD_ + idx) * 512;
  unsigned int xx = *(const unsigned int*)&x[t * 2];        // 2 bf16
  float v0 = bf2f((unsigned short)(xx & 0xffff));
  float v1 = bf2f((unsigned short)(xx >> 16));
  float s = v0 + v1, sq = v0*v0 + v1*v1;
  lma_red2(s, sq);
  float mean = s / 512.f;
  float var = sq / 512.f - mean * mean;
  float rstd = rsqrtf(fmaxf(var, 0.f) + 1e-12f);
  float2 gv = *(const float2*)&g[t * 2];
  float2 bv = *(const float2*)&bb[t * 2];
  float o0 = (v0 - mean) * rstd * gv.x + bv.x;
  float o1 = (v1 - mean) * rstd * gv.y + bv.y;
  *(unsigned int*)&o[t * 2] = cvtpk(o0, o1);
}

// ---------------------------------------------------------------- attn LN: LN(residual(hidden)+[pf,pb](bf16)) -> bf16 (M_ x 1024)
// round-17: f32x4 hidden loads + u32x2 bf16 loads (thread t owns d = t*4..t*4+3;
// half-select is wave-uniform: waves 0-1 f-half, waves 2-3 b-half) + packed store
__global__ __launch_bounds__(256) void lma_attn_ln(const unsigned short* __restrict__ pf,
                                                   const unsigned short* __restrict__ pb,
                                                   const float* __restrict__ hidden,
                                                   const float* __restrict__ g, const float* __restrict__ bb,
                                                   unsigned short* __restrict__ out){
  int m = blockIdx.x, t = threadIdx.x;
  int b = m / S2_, s = m - b * S2_;
  const float* hf = hidden + ((size_t)s       * B_ + b) * 1024;
  const float* hb = hidden + ((size_t)(s + 2) * B_ + b) * 1024;
  const int d0 = t * 4;                      // 0..1020
  const bool fh = (d0 < 512);
  const float* hrow = fh ? hf : hb;          // hb indexed by full d (512..1023)
  const unsigned short* prow = (fh ? pf : pb) + (size_t)m * 512;
  const int dd = d0 & 511;
  f32x4 hv = *(const f32x4*)&hrow[d0];
  u32x2 pv2 = *(const u32x2*)&prow[dd];      // 4 bf16
  float v[4];
  v[0] = bf2f((unsigned short)(pv2[0] & 0xffff)) + hv[0];
  v[1] = bf2f((unsigned short)(pv2[0] >> 16))    + hv[1];
  v[2] = bf2f((unsigned short)(pv2[1] & 0xffff)) + hv[2];
  v[3] = bf2f((unsigned short)(pv2[1] >> 16))    + hv[3];
  float sum = v[0] + v[1] + v[2] + v[3];
  float sq  = v[0]*v[0] + v[1]*v[1] + v[2]*v[2] + v[3]*v[3];
  lma_red2(sum, sq);
  float mean = sum / 1024.f;
  float var = sq / 1024.f - mean * mean;
  float rstd = rsqrtf(fmaxf(var, 0.f) + 1e-12f);
  f32x4 gv = *(const f32x4*)&g[d0];
  f32x4 bv = *(const f32x4*)&bb[d0];
  float o0 = (v[0] - mean) * rstd * gv[0] + bv[0];
  float o1 = (v[1] - mean) * rstd * gv[1] + bv[1];
  float o2 = (v[2] - mean) * rstd * gv[2] + bv[2];
  float o3 = (v[3] - mean) * rstd * gv[3] + bv[3];
  u32x2 pk; pk[0] = cvtpk(o0, o1); pk[1] = cvtpk(o2, o3);
  *(u32x2*)&out[(size_t)m * 1024 + d0] = pk;
}

// ---------------------------------------------------------------- combined flash attention v11: KVBLK=128 (2 k-tiles/iter)
// (best-measured 89-90us version; four restructurings falsified against it)
__global__ __launch_bounds__(256, 4) void lma_attn11(const unsigned short* __restrict__ Q2,
                                                     const unsigned short* __restrict__ KV2,
                                                     const unsigned short* __restrict__ VT2,
                                                     unsigned short* __restrict__ CT2,
                                                     const int* __restrict__ lens){
  __shared__ unsigned short Kl[2][64*64];
  __shared__ unsigned short Vl[2][64*64];
  __shared__ __align__(16) unsigned short Pl[4][16*64];

  const int tid = threadIdx.x;
  const int w = tid >> 6, lane = tid & 63, quad = lane >> 4, l16 = lane & 15;
  const int id = blockIdx.x;                 // 1024 blocks: [qt:4][h:3][b:3]
  const int qt = id >> 6, h = (id >> 3) & 7, b = id & 7;
  const int L2 = lens[b] - 2;
  const int q0wg = qt * 64;
  const int q0 = q0wg + w * 16;
  const int qg = q0 + l16;
  const int qload = (qg > S2_-1) ? (S2_-1) : qg;

  const size_t qbase  = ((size_t)b * S2_) * 512  + h * 64;
  const size_t kbase  = ((size_t)b * S2_) * 1024 + h * 64;
  const size_t vtbase = ((size_t)(b * 8 + h) * 64) * 1024;
  char* Pb = (char*)&Pl[w][0];

  const int lrow = lane >> 3;
  const int g0s  = (lane & 7) ^ lrow;
  const int x7   = l16 & 7;
  const int x7s  = x7 << 4;

  for (int fb = 0; fb < 2; fb++) {
    const int backward = fb;
    const unsigned short* Q  = Q2  + (size_t)fb * PAD_ * 512;
    const unsigned short* Kx = KV2 + (size_t)fb * PAD_ * 1024;
    const unsigned short* VT = VT2 + (size_t)fb * VTS_;
    unsigned short* CTX      = CT2 + (size_t)fb * PAD_ * 512;

    bf16x8 qf[2];
    {
      const unsigned short* qp = Q + qbase + (size_t)qload * 512 + quad * 8;
      qf[0] = *(const bf16x8*)(qp);
      qf[1] = *(const bf16x8*)(qp + 32);
    }

    float mi = -3e38f, li = 0.f;
    f32x4 ot[4];
    #pragma unroll
    for (int f = 0; f < 4; f++) ot[f] = f32x4{0.f,0.f,0.f,0.f};

    int klo = 0, khi = S2_ - 1;
    if (q0wg + 63 < L2) {
      if (!backward) khi = q0wg + 63;
      else { klo = q0wg; khi = L2 - 1; }
    }

    for (int kt0 = klo; kt0 <= khi; kt0 += 128) {
      const bool h2 = (kt0 + 64 <= khi);       // block-uniform
      const int span = h2 ? 127 : 63;

      #pragma unroll
      for (int c = 0; c < 2; c++) {
        int r = w*16 + c*8 + lrow;
        int kr = kt0 + r; if (kr > S2_-1) kr = S2_-1;
        glds16(Kx + kbase + (size_t)kr * 1024 + g0s * 8, &Kl[0][(w*16 + c*8) * 64]);
        glds16(VT + vtbase + (size_t)r * 1024 + kt0 + g0s * 8, &Vl[0][(w*16 + c*8) * 64]);
      }
      if (h2) {
        #pragma unroll
        for (int c = 0; c < 2; c++) {
          int r = w*16 + c*8 + lrow;
          int kr = kt0 + 64 + r; if (kr > S2_-1) kr = S2_-1;
          glds16(Kx + kbase + (size_t)kr * 1024 + g0s * 8, &Kl[1][(w*16 + c*8) * 64]);
          glds16(VT + vtbase + (size_t)r * 1024 + (kt0 + 64) + g0s * 8, &Vl[1][(w*16 + c*8) * 64]);
        }
      }
      __syncthreads();

      f32x4 st[8];
      {
        bf16x8 kf[4][2];
        #pragma unroll
        for (int sub = 0; sub < 4; sub++) {
          const unsigned short* kp = &Kl[0][(sub*16 + l16) * 64];
          kf[sub][0] = *(const bf16x8*)(kp + (( quad      ^ x7) * 8));
          kf[sub][1] = *(const bf16x8*)(kp + (((quad + 4) ^ x7) * 8));
        }
        __builtin_amdgcn_s_setprio(1);
        #pragma unroll
        for (int sub = 0; sub < 4; sub++) {
          f32x4 s = f32x4{0.f,0.f,0.f,0.f};
          s = __builtin_amdgcn_mfma_f32_16x16x32_bf16(kf[sub][0], qf[0], s, 0, 0, 0);
          s = __builtin_amdgcn_mfma_f32_16x16x32_bf16(kf[sub][1], qf[1], s, 0, 0, 0);
          st[sub] = s;
        }
        __builtin_amdgcn_s_setprio(0);
      }
      if (h2) {
        bf16x8 kf[4][2];
        #pragma unroll
        for (int sub = 0; sub < 4; sub++) {
          const unsigned short* kp = &Kl[1][(sub*16 + l16) * 64];
          kf[sub][0] = *(const bf16x8*)(kp + (( quad      ^ x7) * 8));
          kf[sub][1] = *(const bf16x8*)(kp + (((quad + 4) ^ x7) * 8));
        }
        __builtin_amdgcn_s_setprio(1);
        #pragma unroll
        for (int sub = 0; sub < 4; sub++) {
          f32x4 s = f32x4{0.f,0.f,0.f,0.f};
          s = __builtin_amdgcn_mfma_f32_16x16x32_bf16(kf[sub][0], qf[0], s, 0, 0, 0);
          s = __builtin_amdgcn_mfma_f32_16x16x32_bf16(kf[sub][1], qf[1], s, 0, 0, 0);
          st[4 + sub] = s;
        }
        __builtin_amdgcn_s_setprio(0);
      }

      {
        bool tail = (kt0 + span > S2_ - 1);
        bool full;
        if (!backward) full = !tail && ((kt0 + span <= q0) || (q0 >= L2));
        else           full = !tail && ((q0 >= L2) || ((kt0 >= q0 + 15) && (kt0 + span < L2)));
        if (!full) {
          #pragma unroll
          for (int sub = 0; sub < 4; sub++) {
            #pragma unroll
            for (int r = 0; r < 4; r++) {
              int kg = kt0 + sub*16 + quad*4 + r;
              bool ok;
              if (!backward) ok = (kg < S2_) && ((qg >= L2) || (kg <= qg));
              else           ok = (kg < S2_) && ((qg >= L2) || ((kg >= qg) && (kg < L2)));
              if (!ok) st[sub][r] = -3e38f;
            }
          }
          if (h2) {
            #pragma unroll
            for (int sub = 0; sub < 4; sub++) {
              #pragma unroll
              for (int r = 0; r < 4; r++) {
                int kg = kt0 + 64 + sub*16 + quad*4 + r;
                bool ok;
                if (!backward) ok = (kg < S2_) && ((qg >= L2) || (kg <= qg));
                else           ok = (kg < S2_) && ((qg >= L2) || ((kg >= qg) && (kg < L2)));
                if (!ok) st[4 + sub][r] = -3e38f;
              }
            }
          }
        }
      }

      float mx = -3e38f;
      #pragma unroll
      for (int sub = 0; sub < 4; sub++)
        #pragma unroll
        for (int r = 0; r < 4; r++) mx = fmaxf(mx, st[sub][r]);
      if (h2) {
        #pragma unroll
        for (int sub = 4; sub < 8; sub++)
          #pragma unroll
          for (int r = 0; r < 4; r++) mx = fmaxf(mx, st[sub][r]);
      }
      mx = fmaxf(mx, __shfl_xor(mx, 16));
      mx = fmaxf(mx, __shfl_xor(mx, 32));

      if (__any(mx > mi + 11.f)) {
        float mn = fmaxf(mi, mx);
        float al = fexp2(mi - mn);
        li *= al;
        #pragma unroll
        for (int f = 0; f < 4; f++)
          #pragma unroll
          for (int r = 0; r < 4; r++) ot[f][r] *= al;
        mi = mn;
      }

      float rs = 0.f;
      #pragma unroll
      for (int sub = 0; sub < 4; sub++)
        #pragma unroll
        for (int r = 0; r < 4; r++) {
          float p = fexp2(st[sub][r] - mi);
          st[sub][r] = p; rs += p;
        }
      if (h2) {
        #pragma unroll
        for (int sub = 4; sub < 8; sub++)
          #pragma unroll
          for (int r = 0; r < 4; r++) {
            float p = fexp2(st[sub][r] - mi);
            st[sub][r] = p; rs += p;
          }
      }
      rs += __shfl_xor(rs, 16);
      rs += __shfl_xor(rs, 32);
      li += rs;

      #pragma unroll
      for (int sub = 0; sub < 4; sub++) {
        u32x2 pk2;
        pk2[0] = cvtpk(st[sub][0], st[sub][1]);
        pk2[1] = cvtpk(st[sub][2], st[sub][3]);
        *(u32x2*)(Pb + (l16*128 + ((sub*32 + quad*8) ^ x7s))) = pk2;
      }
      {
        bf16x8 pfr0 = *(const bf16x8*)(Pb + (l16*128 + (( 0 + quad*16) ^ x7s)));
        bf16x8 pfr1 = *(const bf16x8*)(Pb + (l16*128 + ((64 + quad*16) ^ x7s)));
        bf16x8 vf[4][2];
        #pragma unroll
        for (int f = 0; f < 4; f++) {
          const unsigned short* vp = &Vl[0][(f*16 + l16) * 64];
          vf[f][0] = *(const bf16x8*)(vp + (( quad      ^ x7) * 8));
          vf[f][1] = *(const bf16x8*)(vp + (((quad + 4) ^ x7) * 8));
        }
        __builtin_amdgcn_s_setprio(1);
        #pragma unroll
        for (int f = 0; f < 4; f++) {
          ot[f] = __builtin_amdgcn_mfma_f32_16x16x32_bf16(vf[f][0], pfr0, ot[f], 0, 0, 0);
          ot[f] = __builtin_amdgcn_mfma_f32_16x16x32_bf16(vf[f][1], pfr1, ot[f], 0, 0, 0);
        }
        __builtin_amdgcn_s_setprio(0);
      }
      if (h2) {
        #pragma unroll
        for (int sub = 0; sub < 4; sub++) {
          u32x2 pk2;
          pk2[0] = cvtpk(st[4+sub][0], st[4+sub][1]);
          pk2[1] = cvtpk(st[4+sub][2], st[4+sub][3]);
          *(u32x2*)(Pb + (l16*128 + ((sub*32 + quad*8) ^ x7s))) = pk2;
        }
        bf16x8 pfr0 = *(const bf16x8*)(Pb + (l16*128 + (( 0 + quad*16) ^ x7s)));
        bf16x8 pfr1 = *(const bf16x8*)(Pb + (l16*128 + ((64 + quad*16) ^ x7s)));
        bf16x8 vf[4][2];
        #pragma unroll
        for (int f = 0; f < 4; f++) {
          const unsigned short* vp = &Vl[1][(f*16 + l16) * 64];
          vf[f][0] = *(const bf16x8*)(vp + (( quad      ^ x7) * 8));
          vf[f][1] = *(const bf16x8*)(vp + (((quad + 4) ^ x7) * 8));
        }
        __builtin_amdgcn_s_setprio(1);
        #pragma unroll
        for (int f = 0; f < 4; f++) {
          ot[f] = __builtin_amdgcn_mfma_f32_16x16x32_bf16(vf[f][0], pfr0, ot[f], 0, 0, 0);
          ot[f] = __builtin_amdgcn_mfma_f32_16x16x32_bf16(vf[f][1], pfr1, ot[f], 0, 0, 0);
        }
        __builtin_amdgcn_s_setprio(0);
      }
      __syncthreads();
    }

    if (qg < S2_) {
      float rcp = 1.f / li;
      #pragma unroll
      for (int f = 0; f < 4; f++) {
        ushort4 pk;
        pk.x = f2bf(ot[f][0] * rcp); pk.y = f2bf(ot[f][1] * rcp);
        pk.z = f2bf(ot[f][2] * rcp); pk.w = f2bf(ot[f][3] * rcp);
        *(ushort4*)&CTX[qbase + (size_t)qg * 512 + f*16 + quad*4] = pk;
      }
    }
  }
}

// ----------------------------------------------------------------
extern "C" void kernel_launch(void* const* d_in, const int* in_sizes, int n_in,
                              void* d_out, int out_size, void* d_ws, size_t ws_size,
                              hipStream_t stream)
{
  const float* hidden = (const float*)d_in[0];
  const int*   lens   = (const int*)d_in[1];
  const float* fw[14]; for (int i = 0; i < 14; i++) fw[i] = (const float*)d_in[2 + i];
  const float* bw[14]; for (int i = 0; i < 14; i++) bw[i] = (const float*)d_in[16 + i];
  const float* attn_g = (const float*)d_in[30];
  const float* attn_b = (const float*)d_in[31];
  const float* o_w1 = (const float*)d_in[32];
  const float* o_b1 = (const float*)d_in[33];
  const float* o_w2 = (const float*)d_in[34];
  const float* o_b2 = (const float*)d_in[35];
  const float* o_lng = (const float*)d_in[36];
  const float* o_lnb = (const float*)d_in[37];

  char* ws = (char*)d_ws;
  size_t off = 0;
  auto alloc = [&](size_t bytes)->char* {
    off = (off + 255) & ~(size_t)255;
    char* p = ws + off; off += bytes; return p;
  };

  unsigned short* fw1t = (unsigned short*)alloc((size_t)1024*1024*2);
  unsigned short* fw2t = (unsigned short*)alloc((size_t)512*1024*2);
  unsigned short* fqt  = (unsigned short*)alloc((size_t)512*512*2);
  unsigned short* fkvt = (unsigned short*)alloc((size_t)1024*512*2);  // [K(512 rows); V(512 rows)]
  unsigned short* fot  = (unsigned short*)alloc((size_t)512*512*2);
  unsigned short* bw1t = (unsigned short*)alloc((size_t)1024*1024*2);
  unsigned short* bw2t = (unsigned short*)alloc((size_t)512*1024*2);
  unsigned short* bqt  = (unsigned short*)alloc((size_t)512*512*2);
  unsigned short* bkvt = (unsigned short*)alloc((size_t)1024*512*2);
  unsigned short* bot  = (unsigned short*)alloc((size_t)512*512*2);
  unsigned short* ow1t = (unsigned short*)alloc((size_t)1024*1024*2);
  unsigned short* ow2t = (unsigned short*)alloc((size_t)1024*1024*2);
  float*          biasKV = (float*)alloc(2048*4);

  unsigned short* Xb   = (unsigned short*)alloc((size_t)M_*1024*2);
  unsigned short* big1 = (unsigned short*)alloc((size_t)2*PAD_*1024*2);
  float*          big2 = (float*)alloc((size_t)2*PAD_*512*4);
  unsigned short* LQCT = (unsigned short*)alloc((size_t)2*PAD_*512*2);
  unsigned short* Q2   = (unsigned short*)alloc((size_t)2*PAD_*512*2);

  unsigned short* H12 = big1, *KV2 = big1, *H1o = big1;
  // big2 partitions: [0 .. 2*VTS_) = T12b (bf16) then VT2 (bf16);
  //                  [2*VTS_ .. 4*VTS_) = P2b (bf16 out-proj). Exactly fills big2.
  unsigned short* T12b = (unsigned short*)big2;
  unsigned short* VT2  = (unsigned short*)big2;
  unsigned short* P2b  = (unsigned short*)big2 + 2*VTS_;
  unsigned short* LQ2 = LQCT, *CT2 = LQCT;

  lma_prep_x<<<M_, 256, 0, stream>>>(hidden, Xb);

  {
    TPack tp;
    const float* srcs[14] = { fw[0], fw[2], fw[6], fw[8], fw[10], fw[12],
                              bw[0], bw[2], bw[6], bw[8], bw[10], bw[12],
                              o_w1, o_w2 };
    unsigned short* dsts[14] = { fw1t, fw2t, fqt, fkvt, fkvt + (size_t)512*512, fot,
                                 bw1t, bw2t, bqt, bkvt, bkvt + (size_t)512*512, bot,
                                 ow1t, ow2t };
    int Ks[14] = {1024,1024,512,512,512,512, 1024,1024,512,512,512,512, 1024,1024};
    int Ns[14] = {1024, 512,512,512,512,512, 1024, 512,512,512,512,512, 1024,1024};
    for (int i = 0; i < 14; i++){ tp.src[i]=srcs[i]; tp.dst[i]=dsts[i]; tp.K[i]=Ks[i]; tp.N[i]=Ns[i]; }
    lma_transpose_all<<<dim3(32, 32, 14), 256, 0, stream>>>(tp);
  }
  lma_biascat<<<8, 256, 0, stream>>>(fw[9], fw[11], bw[9], bw[11], biasKV);

  auto G8 = [&](const unsigned short* A, int lda,
                const unsigned short* B0, const unsigned short* B1,
                const float* b0, const float* b1,
                unsigned short* C, int ldc, int M, int N, int K, int mode, int amap){
    int nmt = M / 256;
    lma_gemm8<<<dim3(nmt * (N/256)), 512, 0, stream>>>(A, lda, B0, B1, b0, b1, C, ldc, M, N, K, mode, amap, nmt);
  };
  auto G8W = [&](const unsigned short* A, int lda,
                 const unsigned short* B0, const unsigned short* B1,
                 const float* b0, const float* b1,
                 void* C, int ldc, int M, int N, int K, int mode){
    int nmt = (M + 127) / 128;
    lma_gemm8w<<<dim3(nmt * (N/256)), 512, 0, stream>>>(A, lda, B0, B1, b0, b1, C, ldc, M, N, K, mode, nmt);
  };

  // both-branch FFN + LN + projections (rows<8192 = forward, >=8192 = backward)
  G8(Xb, 1024, fw1t, bw1t, fw[1], bw[1], H12, 1024, 2*PAD_, 1024, 1024, 2, 1);   // FFN1+gelu (256^2 8-phase)
  G8W(H12, 1024, fw2t, bw2t, fw[3], bw[3], T12b, 512, 2*PAD_, 512, 1024, 0);     // FFN2 -> bf16 (128x256 8-phase)
  lma_ln2<<<2*M_, 256, 0, stream>>>(T12b, fw[4], fw[5], bw[4], bw[5], LQ2);
  G8W(LQ2, 512, fqt, bqt, fw[7], bw[7], Q2, 512, 2*PAD_, 512, 512, 1);           // Q (x0.125*log2e)
  G8(Xb, 1024, fkvt, bkvt, biasKV, biasKV + 1024, KV2, 1024, 2*PAD_, 1024, 512, 0, 2); // K|V (256^2 8-phase)
  lma_vt2<<<dim3(32, 16, 16), 256, 0, stream>>>(KV2, VT2);

  lma_attn11<<<dim3(1024), 256, 0, stream>>>(Q2, KV2, VT2, CT2, lens);

  G8W(CT2, 512, fot, bot, fw[13], bw[13], P2b, 512, 2*PAD_, 512, 512, 0);        // out proj -> bf16

  lma_attn_ln<<<M_, 256, 0, stream>>>(P2b, P2b + (size_t)PAD_*512, hidden, attn_g, attn_b, Xb);

  G8W(Xb, 1024, ow1t, ow1t, o_b1, o_b1, H1o, 1024, M_, 1024, 1024, 2);           // out FFN1+gelu
  G8W(H1o, 1024, ow2t, ow2t, o_b2, o_b2, (float*)d_out, 1024, M_, 1024, 1024, 4); // out FFN2 -> d_out (remapped)
  lma_ln<<<M_, 256, 0, stream>>>((float*)d_out, o_lng, o_lnb, 1024, nullptr, (float*)d_out);
}